// Round 2
// baseline (4908.326 us; speedup 1.0000x reference)
//
#include <hip/hip_runtime.h>
#include <math.h>

namespace {

constexpr int N_  = 32768;   // nodes
constexpr int S_  = 1024;    // nodes per graph
constexpr int B_  = 32;      // graphs
constexpr int E_  = 262144;  // edges
constexpr int C_  = 128;     // hidden
constexpr int H_  = 4;       // heads
constexpr int DH_ = 32;      // head dim
constexpr int ND_ = 64;
constexpr int PE_ = 16;
constexpr int ED_ = 16;
constexpr float LNE = 1e-5f;

__device__ inline float gelu_tanh(float v) {
  const float c = 0.7978845608028654f;
  return 0.5f * v * (1.0f + tanhf(c * (v + 0.044715f * v * v * v)));
}

// block of 128 threads: sum of v across all threads
__device__ inline float block_sum128(float v, float* red, int t) {
  red[t] = v;
  __syncthreads();
#pragma unroll
  for (int off = 64; off > 0; off >>= 1) {
    if (t < off) red[t] += red[t + off];
    __syncthreads();
  }
  float r = red[0];
  __syncthreads();
  return r;
}

// ---------------- zero a float buffer (graph-capture-safe memset) ----------------
__global__ void k_zero(float4* __restrict__ p, int n4) {
  int i = blockIdx.x * 256 + threadIdx.x;
  if (i < n4) p[i] = make_float4(0.f, 0.f, 0.f, 0.f);
}

// ---------------- fold edge_w2 into elin: fw2[l] = edge_w2 @ elin_w[l],
//                  fb2[l] = edge_b2 @ elin_w[l] + elin_b[l] ----------------
__global__ void k_fuse_w(const float* __restrict__ w2, const float* __restrict__ b2,
                         const float* __restrict__ elin_w, const float* __restrict__ elin_b,
                         float* __restrict__ fw2, float* __restrict__ fb2) {
  int t = threadIdx.x;
  int bid = blockIdx.x;
  int layer = bid / (C_ + 1);
  int k = bid % (C_ + 1);
  const float* el = elin_w + (size_t)layer * C_ * C_;
  if (k < C_) {
    float a = 0.0f;
    for (int m = 0; m < C_; ++m) a += w2[k * C_ + m] * el[m * C_ + t];
    fw2[(size_t)layer * C_ * C_ + k * C_ + t] = a;
  } else {
    float a = elin_b[layer * C_ + t];
    for (int m = 0; m < C_; ++m) a += b2[m] * el[m * C_ + t];
    fb2[layer * C_ + t] = a;
  }
}

// ---------------- node encoder: x = MLP2(concat(xin, pe)) ----------------
__global__ void k_node_enc(const float* __restrict__ xin, const float* __restrict__ pe,
                           const float* __restrict__ w1, const float* __restrict__ b1,
                           const float* __restrict__ w2, const float* __restrict__ b2,
                           float* __restrict__ xout) {
  __shared__ float inL[4][80];
  __shared__ float hidL[4][C_];
  int t = threadIdx.x;
  int row0 = blockIdx.x * 4;
#pragma unroll
  for (int r = 0; r < 4; ++r) {
    int row = row0 + r;
    if (t < ND_) inL[r][t] = xin[(size_t)row * ND_ + t];
    else if (t < 80) inL[r][t] = pe[(size_t)row * PE_ + (t - ND_)];
  }
  __syncthreads();
  float acc[4];
  float bb = b1[t];
#pragma unroll
  for (int r = 0; r < 4; ++r) acc[r] = bb;
  for (int k = 0; k < 80; ++k) {
    float wv = w1[k * C_ + t];
#pragma unroll
    for (int r = 0; r < 4; ++r) acc[r] += inL[r][k] * wv;
  }
#pragma unroll
  for (int r = 0; r < 4; ++r) hidL[r][t] = fmaxf(acc[r], 0.0f);
  __syncthreads();
  float bb2 = b2[t];
#pragma unroll
  for (int r = 0; r < 4; ++r) acc[r] = bb2;
  for (int k = 0; k < C_; ++k) {
    float wv = w2[k * C_ + t];
#pragma unroll
    for (int r = 0; r < 4; ++r) acc[r] += hidL[r][k] * wv;
  }
#pragma unroll
  for (int r = 0; r < 4; ++r) xout[(size_t)(row0 + r) * C_ + t] = acc[r];
}

// ------------- per-layer fused edge pipeline:
//   hidden = relu(ea@ew1 + eb1); acc = hidden@fw2 + fb2;
//   msg = relu(x[src] + acc);  agg[dst] += msg  -------------
__global__ void k_edge_layer(const float* __restrict__ ea, const float* __restrict__ x,
                             const int* __restrict__ src, const int* __restrict__ dst,
                             const float* __restrict__ ew1, const float* __restrict__ eb1,
                             const float* __restrict__ fw2, const float* __restrict__ fb2,
                             float* __restrict__ agg) {
  __shared__ float inL[8][ED_];
  __shared__ float hidL[8][C_];
  int t = threadIdx.x;
  int e0 = blockIdx.x * 8;
  {
    int r = t >> 4, k = t & 15;
    inL[r][k] = ea[(size_t)(e0 + r) * ED_ + k];
  }
  __syncthreads();
  float acc[8];
  float bb = eb1[t];
#pragma unroll
  for (int r = 0; r < 8; ++r) acc[r] = bb;
  for (int k = 0; k < ED_; ++k) {
    float wv = ew1[k * C_ + t];
#pragma unroll
    for (int r = 0; r < 8; ++r) acc[r] += inL[r][k] * wv;
  }
#pragma unroll
  for (int r = 0; r < 8; ++r) hidL[r][t] = fmaxf(acc[r], 0.0f);
  __syncthreads();
  float bb2 = fb2[t];
#pragma unroll
  for (int r = 0; r < 8; ++r) acc[r] = bb2;
  for (int k = 0; k < C_; ++k) {
    float wv = fw2[k * C_ + t];
#pragma unroll
    for (int r = 0; r < 8; ++r) acc[r] += hidL[r][k] * wv;
  }
#pragma unroll
  for (int r = 0; r < 8; ++r) {
    int ed = e0 + r;
    float mv = acc[r] + x[(size_t)src[ed] * C_ + t];
    mv = fmaxf(mv, 0.0f);
    atomicAdd(&agg[(size_t)dst[ed] * C_ + t], mv);
  }
}

// ------------- GIN: hl = LN1(MLP2((1+eps)x + agg) + x) -------------
__global__ void k_gin(const float* __restrict__ x, const float* __restrict__ agg,
                      const float* __restrict__ w1, const float* __restrict__ b1,
                      const float* __restrict__ w2, const float* __restrict__ b2,
                      const float* __restrict__ g, const float* __restrict__ bln,
                      const float* __restrict__ epsarr, int layer,
                      float* __restrict__ hl) {
  __shared__ float inL[4][C_];
  __shared__ float hidL[4][C_];
  __shared__ float red[C_];
  int t = threadIdx.x;
  int row0 = blockIdx.x * 4;
  float epsv = 1.0f + epsarr[layer];
  float xv[4];
#pragma unroll
  for (int r = 0; r < 4; ++r) {
    size_t idx = (size_t)(row0 + r) * C_ + t;
    float xx = x[idx];
    xv[r] = xx;
    inL[r][t] = epsv * xx + agg[idx];
  }
  __syncthreads();
  float acc[4];
  float bb = b1[t];
#pragma unroll
  for (int r = 0; r < 4; ++r) acc[r] = bb;
  for (int k = 0; k < C_; ++k) {
    float wv = w1[k * C_ + t];
#pragma unroll
    for (int r = 0; r < 4; ++r) acc[r] += inL[r][k] * wv;
  }
#pragma unroll
  for (int r = 0; r < 4; ++r) hidL[r][t] = fmaxf(acc[r], 0.0f);
  __syncthreads();
  float bb2 = b2[t];
#pragma unroll
  for (int r = 0; r < 4; ++r) acc[r] = bb2;
  for (int k = 0; k < C_; ++k) {
    float wv = w2[k * C_ + t];
#pragma unroll
    for (int r = 0; r < 4; ++r) acc[r] += hidL[r][k] * wv;
  }
  float gg = g[t], bl = bln[t];
  for (int r = 0; r < 4; ++r) {
    float v = acc[r] + xv[r];
    float mu = block_sum128(v, red, t) * (1.0f / C_);
    float d = v - mu;
    float var = block_sum128(d * d, red, t) * (1.0f / C_);
    hl[(size_t)(row0 + r) * C_ + t] = d * rsqrtf(var + LNE) * gg + bl;
  }
}

// ------------- QKV projection: qkv = x @ Wqkv + b -------------
__global__ void k_qkv(const float* __restrict__ x,
                      const float* __restrict__ w, const float* __restrict__ b,
                      float* __restrict__ qkv) {
  __shared__ float inL[4][C_];
  int t = threadIdx.x;
  int row0 = blockIdx.x * 4;
#pragma unroll
  for (int r = 0; r < 4; ++r) inL[r][t] = x[(size_t)(row0 + r) * C_ + t];
  __syncthreads();
  float acc[4][3];
  float b0 = b[t], b1v = b[t + 128], b2v = b[t + 256];
#pragma unroll
  for (int r = 0; r < 4; ++r) { acc[r][0] = b0; acc[r][1] = b1v; acc[r][2] = b2v; }
  for (int k = 0; k < C_; ++k) {
    float w0 = w[k * 384 + t];
    float w1v = w[k * 384 + t + 128];
    float w2v = w[k * 384 + t + 256];
#pragma unroll
    for (int r = 0; r < 4; ++r) {
      float iv = inL[r][k];
      acc[r][0] += iv * w0;
      acc[r][1] += iv * w1v;
      acc[r][2] += iv * w2v;
    }
  }
#pragma unroll
  for (int r = 0; r < 4; ++r) {
    size_t base = (size_t)(row0 + r) * 384;
    qkv[base + t] = acc[r][0];
    qkv[base + t + 128] = acc[r][1];
    qkv[base + t + 256] = acc[r][2];
  }
}

// ------------- flash attention: attno = softmax(qk^T * scale) v -------------
// grid = B*H*8 blocks, 128 threads, thread = 1 q row, 32-key chunks
__global__ void k_attn(const float* __restrict__ qkv, float* __restrict__ attno) {
  __shared__ float kL[32][32];
  __shared__ float vL[32][32];
  int t = threadIdx.x;
  int bid = blockIdx.x;
  int qt = bid & 7;
  int h = (bid >> 3) & 3;
  int b = bid >> 5;
  int node = b * S_ + qt * 128 + t;
  const float* qrow = qkv + (size_t)node * 384 + h * DH_;
  float4 q4[8];
#pragma unroll
  for (int i = 0; i < 8; ++i) q4[i] = ((const float4*)qrow)[i];
  float m = -1e30f, l = 0.0f;
  float o[32];
#pragma unroll
  for (int d = 0; d < 32; ++d) o[d] = 0.0f;
  const float scale = 0.17677669529663687f;  // 1/sqrt(32)
  for (int kc = 0; kc < 32; ++kc) {
    __syncthreads();
#pragma unroll
    for (int i = 0; i < 2; ++i) {
      int f = t * 2 + i;         // 0..255  -> (row j, float4 d4)
      int j = f >> 3, d4 = f & 7;
      size_t base = (size_t)(b * S_ + kc * 32 + j) * 384 + h * DH_;
      ((float4*)&kL[j][0])[d4] = *(const float4*)(qkv + base + 128 + d4 * 4);
      ((float4*)&vL[j][0])[d4] = *(const float4*)(qkv + base + 256 + d4 * 4);
    }
    __syncthreads();
    float s[32];
    float cm = -1e30f;
#pragma unroll
    for (int j = 0; j < 32; ++j) {
      const float4* kr = (const float4*)&kL[j][0];
      float a = 0.0f;
#pragma unroll
      for (int i = 0; i < 8; ++i) {
        float4 kv = kr[i];
        a += q4[i].x * kv.x + q4[i].y * kv.y + q4[i].z * kv.z + q4[i].w * kv.w;
      }
      s[j] = a * scale;
      cm = fmaxf(cm, s[j]);
    }
    float mn = fmaxf(m, cm);
    float al = __expf(m - mn);
    l *= al;
#pragma unroll
    for (int d = 0; d < 32; ++d) o[d] *= al;
#pragma unroll
    for (int j = 0; j < 32; ++j) {
      float p = __expf(s[j] - mn);
      l += p;
      const float* vr = &vL[j][0];
#pragma unroll
      for (int d = 0; d < 32; ++d) o[d] += p * vr[d];
    }
    m = mn;
  }
  float inv = 1.0f / l;
  float* orow = attno + (size_t)node * C_ + h * DH_;
#pragma unroll
  for (int d = 0; d < 32; ++d) orow[d] = o[d] * inv;
}

// ------------- attn out proj + LN2: ha = LN2(attno@W + b + x), IN-PLACE over attno -------------
__global__ void k_attnout(const float* __restrict__ attno, const float* __restrict__ x,
                          const float* __restrict__ w, const float* __restrict__ b,
                          const float* __restrict__ g, const float* __restrict__ bln,
                          float* __restrict__ ha) {
  __shared__ float inL[4][C_];
  __shared__ float red[C_];
  int t = threadIdx.x;
  int row0 = blockIdx.x * 4;
  float xv[4];
#pragma unroll
  for (int r = 0; r < 4; ++r) {
    size_t idx = (size_t)(row0 + r) * C_ + t;
    inL[r][t] = attno[idx];
    xv[r] = x[idx];
  }
  __syncthreads();
  float acc[4];
  float bb = b[t];
#pragma unroll
  for (int r = 0; r < 4; ++r) acc[r] = bb;
  for (int k = 0; k < C_; ++k) {
    float wv = w[k * C_ + t];
#pragma unroll
    for (int r = 0; r < 4; ++r) acc[r] += inL[r][k] * wv;
  }
  float gg = g[t], bl = bln[t];
  for (int r = 0; r < 4; ++r) {
    float v = acc[r] + xv[r];
    float mu = block_sum128(v, red, t) * (1.0f / C_);
    float d = v - mu;
    float var = block_sum128(d * d, red, t) * (1.0f / C_);
    ha[(size_t)(row0 + r) * C_ + t] = d * rsqrtf(var + LNE) * gg + bl;
  }
}

// ------------- FFN: out=hl+ha; out2=out+MLP2(out,gelu); x += LN3(out2) -------------
__global__ void k_ffn(const float* __restrict__ hl, const float* __restrict__ ha,
                      float* __restrict__ x,
                      const float* __restrict__ w1, const float* __restrict__ b1,
                      const float* __restrict__ w2, const float* __restrict__ b2,
                      const float* __restrict__ g, const float* __restrict__ bln) {
  __shared__ float outL[4][C_];
  __shared__ float hidL[4][2 * C_];
  __shared__ float red[C_];
  int t = threadIdx.x;
  int row0 = blockIdx.x * 4;
  float outv[4];
#pragma unroll
  for (int r = 0; r < 4; ++r) {
    size_t idx = (size_t)(row0 + r) * C_ + t;
    float v = hl[idx] + ha[idx];
    outv[r] = v;
    outL[r][t] = v;
  }
  __syncthreads();
  float acc2[4][2];
  float ba = b1[t], bbv = b1[t + 128];
#pragma unroll
  for (int r = 0; r < 4; ++r) { acc2[r][0] = ba; acc2[r][1] = bbv; }
  for (int k = 0; k < C_; ++k) {
    float wa = w1[k * 256 + t];
    float wb = w1[k * 256 + t + 128];
#pragma unroll
    for (int r = 0; r < 4; ++r) {
      float iv = outL[r][k];
      acc2[r][0] += iv * wa;
      acc2[r][1] += iv * wb;
    }
  }
#pragma unroll
  for (int r = 0; r < 4; ++r) {
    hidL[r][t] = gelu_tanh(acc2[r][0]);
    hidL[r][t + 128] = gelu_tanh(acc2[r][1]);
  }
  __syncthreads();
  float acc[4];
  float b2v = b2[t];
#pragma unroll
  for (int r = 0; r < 4; ++r) acc[r] = b2v;
  for (int k = 0; k < 2 * C_; ++k) {
    float wv = w2[k * C_ + t];
#pragma unroll
    for (int r = 0; r < 4; ++r) acc[r] += hidL[r][k] * wv;
  }
  float gg = g[t], bl = bln[t];
  for (int r = 0; r < 4; ++r) {
    float v = outv[r] + acc[r];
    float mu = block_sum128(v, red, t) * (1.0f / C_);
    float d = v - mu;
    float var = block_sum128(d * d, red, t) * (1.0f / C_);
    size_t idx = (size_t)(row0 + r) * C_ + t;
    x[idx] = x[idx] + d * rsqrtf(var + LNE) * gg + bl;
  }
}

// ------------- post MLP: x += MLP2(x) -------------
__global__ void k_post(float* __restrict__ x,
                       const float* __restrict__ w1, const float* __restrict__ b1,
                       const float* __restrict__ w2, const float* __restrict__ b2) {
  __shared__ float inL[4][C_];
  __shared__ float hidL[4][C_];
  int t = threadIdx.x;
  int row0 = blockIdx.x * 4;
  float xv[4];
#pragma unroll
  for (int r = 0; r < 4; ++r) {
    size_t idx = (size_t)(row0 + r) * C_ + t;
    xv[r] = x[idx];
    inL[r][t] = xv[r];
  }
  __syncthreads();
  float acc[4];
  float bb = b1[t];
#pragma unroll
  for (int r = 0; r < 4; ++r) acc[r] = bb;
  for (int k = 0; k < C_; ++k) {
    float wv = w1[k * C_ + t];
#pragma unroll
    for (int r = 0; r < 4; ++r) acc[r] += inL[r][k] * wv;
  }
#pragma unroll
  for (int r = 0; r < 4; ++r) hidL[r][t] = fmaxf(acc[r], 0.0f);
  __syncthreads();
  float bb2 = b2[t];
#pragma unroll
  for (int r = 0; r < 4; ++r) acc[r] = bb2;
  for (int k = 0; k < C_; ++k) {
    float wv = w2[k * C_ + t];
#pragma unroll
    for (int r = 0; r < 4; ++r) acc[r] += hidL[r][k] * wv;
  }
#pragma unroll
  for (int r = 0; r < 4; ++r) {
    size_t idx = (size_t)(row0 + r) * C_ + t;
    x[idx] = xv[r] + acc[r];
  }
}

// ------------- mean pool per graph -------------
__global__ void k_pool(const float* __restrict__ x, float* __restrict__ gmean) {
  int t = threadIdx.x;
  int b = blockIdx.x;
  float s = 0.0f;
  for (int sidx = 0; sidx < S_; ++sidx) s += x[((size_t)b * S_ + sidx) * C_ + t];
  gmean[b * C_ + t] = s * (1.0f / S_);
}

// ------------- readout: out[b] = MLP2(gmean)  (128->128 relu ->1) -------------
__global__ void k_readout(const float* __restrict__ gmean,
                          const float* __restrict__ w1, const float* __restrict__ b1,
                          const float* __restrict__ w2, const float* __restrict__ b2,
                          float* __restrict__ out) {
  __shared__ float gL[C_];
  __shared__ float red[C_];
  int t = threadIdx.x;
  int b = blockIdx.x;
  gL[t] = gmean[b * C_ + t];
  __syncthreads();
  float acc = b1[t];
  for (int k = 0; k < C_; ++k) acc += gL[k] * w1[k * C_ + t];
  float hid = fmaxf(acc, 0.0f);
  float part = hid * w2[t];
  float tot = block_sum128(part, red, t);
  if (t == 0) out[b] = tot + b2[0];
}

}  // namespace

extern "C" void kernel_launch(void* const* d_in, const int* in_sizes, int n_in,
                              void* d_out, int out_size, void* d_ws, size_t ws_size,
                              hipStream_t stream) {
  const float* in_x      = (const float*)d_in[0];
  const int*   edge_idx  = (const int*)d_in[1];
  // d_in[2] = batch (unused: graphs are contiguous S-blocks)
  const float* edge_attr = (const float*)d_in[3];
  const float* lap_pe    = (const float*)d_in[4];
  const float* node_w1 = (const float*)d_in[5];
  const float* node_b1 = (const float*)d_in[6];
  const float* node_w2 = (const float*)d_in[7];
  const float* node_b2 = (const float*)d_in[8];
  const float* edge_w1 = (const float*)d_in[9];
  const float* edge_b1 = (const float*)d_in[10];
  const float* edge_w2 = (const float*)d_in[11];
  const float* edge_b2 = (const float*)d_in[12];
  const float* eps     = (const float*)d_in[13];
  const float* gin_w1  = (const float*)d_in[14];
  const float* gin_b1  = (const float*)d_in[15];
  const float* gin_w2  = (const float*)d_in[16];
  const float* gin_b2  = (const float*)d_in[17];
  const float* elin_w  = (const float*)d_in[18];
  const float* elin_b  = (const float*)d_in[19];
  const float* aqkv_w  = (const float*)d_in[20];
  const float* aqkv_b  = (const float*)d_in[21];
  const float* aout_w  = (const float*)d_in[22];
  const float* aout_b  = (const float*)d_in[23];
  const float* mlp_w1  = (const float*)d_in[24];
  const float* mlp_b1  = (const float*)d_in[25];
  const float* mlp_w2  = (const float*)d_in[26];
  const float* mlp_b2  = (const float*)d_in[27];
  const float* ln1_g   = (const float*)d_in[28];
  const float* ln1_b   = (const float*)d_in[29];
  const float* ln2_g   = (const float*)d_in[30];
  const float* ln2_b   = (const float*)d_in[31];
  const float* ln3_g   = (const float*)d_in[32];
  const float* ln3_b   = (const float*)d_in[33];
  const float* post_w1 = (const float*)d_in[34];
  const float* post_b1 = (const float*)d_in[35];
  const float* post_w2 = (const float*)d_in[36];
  const float* post_b2 = (const float*)d_in[37];
  const float* ro_w1   = (const float*)d_in[38];
  const float* ro_b1   = (const float*)d_in[39];
  const float* ro_w2   = (const float*)d_in[40];
  const float* ro_b2   = (const float*)d_in[41];

  const int* src = edge_idx;
  const int* dst = edge_idx + E_;

  // Workspace layout (floats), total ~= 6*N*C + 66K floats ~= 101 MB:
  //   x    : N*C
  //   qkv  : 3*N*C   (agg aliases its first N*C: agg dead before qkv written)
  //   hl   : N*C     (gmean aliases hl after last layer)
  //   attno: N*C     (ha written in-place over attno)
  //   fw2  : L*C*C, fb2 : L*C
  float* ws = (float*)d_ws;
  float* x     = ws;                          // N*C
  float* qkv   = x + (size_t)N_ * C_;         // 3*N*C
  float* agg   = qkv;                         // aliases qkv[0 : N*C]
  float* hl    = qkv + (size_t)N_ * 3 * C_;   // N*C
  float* attno = hl + (size_t)N_ * C_;        // N*C
  float* ha    = attno;                       // in-place
  float* fw2   = attno + (size_t)N_ * C_;     // L*C*C
  float* fb2   = fw2 + (size_t)4 * C_ * C_;   // L*C
  float* gmean = hl;                          // alias (hl dead after last ffn)

  float* out = (float*)d_out;

  dim3 blk(128);

  // fold edge_w2 @ elin_w[l] once per launch
  k_fuse_w<<<4 * (C_ + 1), blk, 0, stream>>>(edge_w2, edge_b2, elin_w, elin_b, fw2, fb2);

  k_node_enc<<<N_ / 4, blk, 0, stream>>>(in_x, lap_pe, node_w1, node_b1, node_w2, node_b2, x);

  for (int i = 0; i < 4; ++i) {
    k_zero<<<(N_ * C_ / 4 + 255) / 256, 256, 0, stream>>>((float4*)agg, N_ * C_ / 4);
    k_edge_layer<<<E_ / 8, blk, 0, stream>>>(edge_attr, x, src, dst,
                                             edge_w1, edge_b1,
                                             fw2 + (size_t)i * C_ * C_, fb2 + i * C_, agg);
    k_gin<<<N_ / 4, blk, 0, stream>>>(x, agg,
                                      gin_w1 + (size_t)i * C_ * C_, gin_b1 + i * C_,
                                      gin_w2 + (size_t)i * C_ * C_, gin_b2 + i * C_,
                                      ln1_g + i * C_, ln1_b + i * C_, eps, i, hl);
    k_qkv<<<N_ / 4, blk, 0, stream>>>(x, aqkv_w + (size_t)i * C_ * 384, aqkv_b + i * 384, qkv);
    k_attn<<<B_ * H_ * 8, blk, 0, stream>>>(qkv, attno);
    k_attnout<<<N_ / 4, blk, 0, stream>>>(attno, x,
                                          aout_w + (size_t)i * C_ * C_, aout_b + i * C_,
                                          ln2_g + i * C_, ln2_b + i * C_, ha);
    k_ffn<<<N_ / 4, blk, 0, stream>>>(hl, ha, x,
                                      mlp_w1 + (size_t)i * C_ * 256, mlp_b1 + i * 256,
                                      mlp_w2 + (size_t)i * 256 * C_, mlp_b2 + i * C_,
                                      ln3_g + i * C_, ln3_b + i * C_);
  }

  k_post<<<N_ / 4, blk, 0, stream>>>(x, post_w1, post_b1, post_w2, post_b2);
  k_pool<<<B_, blk, 0, stream>>>(x, gmean);
  k_readout<<<B_, blk, 0, stream>>>(gmean, ro_w1, ro_b1, ro_w2, ro_b2, out);
}

// Round 3
// 2761.048 us; speedup vs baseline: 1.7777x; 1.7777x over previous
//
#include <hip/hip_runtime.h>
#include <math.h>

namespace {

constexpr int N_  = 32768;   // nodes
constexpr int S_  = 1024;    // nodes per graph
constexpr int B_  = 32;      // graphs
constexpr int E_  = 262144;  // edges
constexpr int C_  = 128;     // hidden
constexpr int ND_ = 64;
constexpr int PE_ = 16;
constexpr int ED_ = 16;
constexpr float LNE = 1e-5f;

typedef __attribute__((ext_vector_type(8))) short short8;
typedef __attribute__((ext_vector_type(4))) float floatx4;

__device__ inline float gelu_tanh(float v) {
  const float c = 0.7978845608028654f;
  return 0.5f * v * (1.0f + tanhf(c * (v + 0.044715f * v * v * v)));
}

__device__ inline unsigned short f2bf_u(float f) {
  unsigned u = __float_as_uint(f);
  u += 0x7fff + ((u >> 16) & 1);
  return (unsigned short)(u >> 16);
}

// block of 128 threads: sum of v across all threads
__device__ inline float block_sum128(float v, float* red, int t) {
  red[t] = v;
  __syncthreads();
#pragma unroll
  for (int off = 64; off > 0; off >>= 1) {
    if (t < off) red[t] += red[t + off];
    __syncthreads();
  }
  float r = red[0];
  __syncthreads();
  return r;
}

// ---------------- zero a float buffer (graph-capture-safe memset) ----------------
__global__ void k_zero(float4* __restrict__ p, int n4) {
  int i = blockIdx.x * 256 + threadIdx.x;
  if (i < n4) p[i] = make_float4(0.f, 0.f, 0.f, 0.f);
}

// ---------------- fold edge_w2 into elin ----------------
__global__ void k_fuse_w(const float* __restrict__ w2, const float* __restrict__ b2,
                         const float* __restrict__ elin_w, const float* __restrict__ elin_b,
                         float* __restrict__ fw2, float* __restrict__ fb2) {
  int t = threadIdx.x;
  int bid = blockIdx.x;
  int layer = bid / (C_ + 1);
  int k = bid % (C_ + 1);
  const float* el = elin_w + (size_t)layer * C_ * C_;
  if (k < C_) {
    float a = 0.0f;
    for (int m = 0; m < C_; ++m) a += w2[k * C_ + m] * el[m * C_ + t];
    fw2[(size_t)layer * C_ * C_ + k * C_ + t] = a;
  } else {
    float a = elin_b[layer * C_ + t];
    for (int m = 0; m < C_; ++m) a += b2[m] * el[m * C_ + t];
    fb2[layer * C_ + t] = a;
  }
}

// ---------------- node encoder ----------------
__global__ void k_node_enc(const float* __restrict__ xin, const float* __restrict__ pe,
                           const float* __restrict__ w1, const float* __restrict__ b1,
                           const float* __restrict__ w2, const float* __restrict__ b2,
                           float* __restrict__ xout) {
  __shared__ float inL[4][80];
  __shared__ float hidL[4][C_];
  int t = threadIdx.x;
  int row0 = blockIdx.x * 4;
#pragma unroll
  for (int r = 0; r < 4; ++r) {
    int row = row0 + r;
    if (t < ND_) inL[r][t] = xin[(size_t)row * ND_ + t];
    else if (t < 80) inL[r][t] = pe[(size_t)row * PE_ + (t - ND_)];
  }
  __syncthreads();
  float acc[4];
  float bb = b1[t];
#pragma unroll
  for (int r = 0; r < 4; ++r) acc[r] = bb;
  for (int k = 0; k < 80; ++k) {
    float wv = w1[k * C_ + t];
#pragma unroll
    for (int r = 0; r < 4; ++r) acc[r] += inL[r][k] * wv;
  }
#pragma unroll
  for (int r = 0; r < 4; ++r) hidL[r][t] = fmaxf(acc[r], 0.0f);
  __syncthreads();
  float bb2 = b2[t];
#pragma unroll
  for (int r = 0; r < 4; ++r) acc[r] = bb2;
  for (int k = 0; k < C_; ++k) {
    float wv = w2[k * C_ + t];
#pragma unroll
    for (int r = 0; r < 4; ++r) acc[r] += hidL[r][k] * wv;
  }
#pragma unroll
  for (int r = 0; r < 4; ++r) xout[(size_t)(row0 + r) * C_ + t] = acc[r];
}

// ------------- fused edge pipeline -------------
__global__ void k_edge_layer(const float* __restrict__ ea, const float* __restrict__ x,
                             const int* __restrict__ src, const int* __restrict__ dst,
                             const float* __restrict__ ew1, const float* __restrict__ eb1,
                             const float* __restrict__ fw2, const float* __restrict__ fb2,
                             float* __restrict__ agg) {
  __shared__ float inL[8][ED_];
  __shared__ float hidL[8][C_];
  int t = threadIdx.x;
  int e0 = blockIdx.x * 8;
  {
    int r = t >> 4, k = t & 15;
    inL[r][k] = ea[(size_t)(e0 + r) * ED_ + k];
  }
  __syncthreads();
  float acc[8];
  float bb = eb1[t];
#pragma unroll
  for (int r = 0; r < 8; ++r) acc[r] = bb;
  for (int k = 0; k < ED_; ++k) {
    float wv = ew1[k * C_ + t];
#pragma unroll
    for (int r = 0; r < 8; ++r) acc[r] += inL[r][k] * wv;
  }
#pragma unroll
  for (int r = 0; r < 8; ++r) hidL[r][t] = fmaxf(acc[r], 0.0f);
  __syncthreads();
  float bb2 = fb2[t];
#pragma unroll
  for (int r = 0; r < 8; ++r) acc[r] = bb2;
  for (int k = 0; k < C_; ++k) {
    float wv = fw2[k * C_ + t];
#pragma unroll
    for (int r = 0; r < 8; ++r) acc[r] += hidL[r][k] * wv;
  }
#pragma unroll
  for (int r = 0; r < 8; ++r) {
    int ed = e0 + r;
    float mv = acc[r] + x[(size_t)src[ed] * C_ + t];
    mv = fmaxf(mv, 0.0f);
    atomicAdd(&agg[(size_t)dst[ed] * C_ + t], mv);
  }
}

// ------------- GIN -------------
__global__ void k_gin(const float* __restrict__ x, const float* __restrict__ agg,
                      const float* __restrict__ w1, const float* __restrict__ b1,
                      const float* __restrict__ w2, const float* __restrict__ b2,
                      const float* __restrict__ g, const float* __restrict__ bln,
                      const float* __restrict__ epsarr, int layer,
                      float* __restrict__ hl) {
  __shared__ float inL[4][C_];
  __shared__ float hidL[4][C_];
  __shared__ float red[C_];
  int t = threadIdx.x;
  int row0 = blockIdx.x * 4;
  float epsv = 1.0f + epsarr[layer];
  float xv[4];
#pragma unroll
  for (int r = 0; r < 4; ++r) {
    size_t idx = (size_t)(row0 + r) * C_ + t;
    float xx = x[idx];
    xv[r] = xx;
    inL[r][t] = epsv * xx + agg[idx];
  }
  __syncthreads();
  float acc[4];
  float bb = b1[t];
#pragma unroll
  for (int r = 0; r < 4; ++r) acc[r] = bb;
  for (int k = 0; k < C_; ++k) {
    float wv = w1[k * C_ + t];
#pragma unroll
    for (int r = 0; r < 4; ++r) acc[r] += inL[r][k] * wv;
  }
#pragma unroll
  for (int r = 0; r < 4; ++r) hidL[r][t] = fmaxf(acc[r], 0.0f);
  __syncthreads();
  float bb2 = b2[t];
#pragma unroll
  for (int r = 0; r < 4; ++r) acc[r] = bb2;
  for (int k = 0; k < C_; ++k) {
    float wv = w2[k * C_ + t];
#pragma unroll
    for (int r = 0; r < 4; ++r) acc[r] += hidL[r][k] * wv;
  }
  float gg = g[t], bl = bln[t];
  for (int r = 0; r < 4; ++r) {
    float v = acc[r] + xv[r];
    float mu = block_sum128(v, red, t) * (1.0f / C_);
    float d = v - mu;
    float var = block_sum128(d * d, red, t) * (1.0f / C_);
    hl[(size_t)(row0 + r) * C_ + t] = d * rsqrtf(var + LNE) * gg + bl;
  }
}

// ------------- QKV projection -> bf16 qkv -------------
__global__ void k_qkv(const float* __restrict__ x,
                      const float* __restrict__ w, const float* __restrict__ b,
                      unsigned short* __restrict__ qkvb) {
  __shared__ float inL[4][C_];
  int t = threadIdx.x;
  int row0 = blockIdx.x * 4;
#pragma unroll
  for (int r = 0; r < 4; ++r) inL[r][t] = x[(size_t)(row0 + r) * C_ + t];
  __syncthreads();
  float acc[4][3];
  float b0 = b[t], b1v = b[t + 128], b2v = b[t + 256];
#pragma unroll
  for (int r = 0; r < 4; ++r) { acc[r][0] = b0; acc[r][1] = b1v; acc[r][2] = b2v; }
  for (int k = 0; k < C_; ++k) {
    float w0 = w[k * 384 + t];
    float w1v = w[k * 384 + t + 128];
    float w2v = w[k * 384 + t + 256];
#pragma unroll
    for (int r = 0; r < 4; ++r) {
      float iv = inL[r][k];
      acc[r][0] += iv * w0;
      acc[r][1] += iv * w1v;
      acc[r][2] += iv * w2v;
    }
  }
#pragma unroll
  for (int r = 0; r < 4; ++r) {
    size_t base = (size_t)(row0 + r) * 384;
    qkvb[base + t]       = f2bf_u(acc[r][0]);
    qkvb[base + t + 128] = f2bf_u(acc[r][1]);
    qkvb[base + t + 256] = f2bf_u(acc[r][2]);
  }
}

// ------------- MFMA flash attention -------------
// grid = B*H*16 = 2048 blocks, 256 threads (4 waves), 16 q rows per wave,
// 32-key chunks double-buffered in LDS.
// mfma_f32_16x16x32_bf16 layouts (m89/m120-verified):
//   A[m=lane&15][k=quad*8+j], B[k=quad*8+j][n=lane&15], C/D: row=quad*4+reg, col=lane&15
__global__ __launch_bounds__(256) void k_attn_mfma(const unsigned short* __restrict__ qkvb,
                                                   float* __restrict__ attno) {
  __shared__ unsigned short kL[2][32][40];  // [key][dim], pitch 40 -> 2-way (free) on b128
  __shared__ unsigned short vT[2][32][40];  // [dim][key] (transposed)
  __shared__ unsigned short pL[4][16][40];  // per-wave P round-trip
  int tid = threadIdx.x;
  int lane = tid & 63;
  int w = tid >> 6;
  int li = lane & 15;
  int quad = lane >> 4;
  int bid = blockIdx.x;
  int qt = bid & 15;
  int h = (bid >> 4) & 3;
  int b = bid >> 6;
  int qbase = b * S_ + qt * 64 + w * 16;

  short8 qA = *(const short8*)(qkvb + (size_t)(qbase + li) * 384 + h * 32 + quad * 8);

  floatx4 o0 = {0.f, 0.f, 0.f, 0.f}, o1 = {0.f, 0.f, 0.f, 0.f};
  float mreg[4] = {-1e30f, -1e30f, -1e30f, -1e30f};
  float lreg[4] = {0.f, 0.f, 0.f, 0.f};
  const float scale = 0.17677669529663687f;  // 1/sqrt(32)

  int half = tid >> 7;   // 0: stage K, 1: stage V
  int tt = tid & 127;
  int j = tt >> 2;       // key row 0..31
  int seg = tt & 3;      // 8-dim group

  for (int kc = 0; kc < 32; ++kc) {
    int buf = kc & 1;
    {
      int node = b * S_ + kc * 32 + j;
      const unsigned short* p = qkvb + (size_t)node * 384 + (half ? 256 : 128) + h * 32 + seg * 8;
      short8 val = *(const short8*)p;
      if (half == 0) {
        *(short8*)&kL[buf][j][seg * 8] = val;
      } else {
#pragma unroll
        for (int i = 0; i < 8; ++i) vT[buf][seg * 8 + i][j] = (unsigned short)val[i];
      }
    }
    __syncthreads();
    short8 kB0 = *(const short8*)&kL[buf][li][quad * 8];
    short8 kB1 = *(const short8*)&kL[buf][16 + li][quad * 8];
    floatx4 z = {0.f, 0.f, 0.f, 0.f};
    floatx4 s0 = __builtin_amdgcn_mfma_f32_16x16x32_bf16(qA, kB0, z, 0, 0, 0);
    floatx4 s1 = __builtin_amdgcn_mfma_f32_16x16x32_bf16(qA, kB1, z, 0, 0, 0);
#pragma unroll
    for (int r = 0; r < 4; ++r) {
      float a0 = s0[r] * scale, a1 = s1[r] * scale;
      float cm = fmaxf(a0, a1);
#pragma unroll
      for (int msk = 1; msk <= 8; msk <<= 1) cm = fmaxf(cm, __shfl_xor(cm, msk));
      float mn = fmaxf(mreg[r], cm);
      float al = __expf(mreg[r] - mn);
      mreg[r] = mn;
      float p0 = __expf(a0 - mn), p1 = __expf(a1 - mn);
      float rs = p0 + p1;
#pragma unroll
      for (int msk = 1; msk <= 8; msk <<= 1) rs += __shfl_xor(rs, msk);
      lreg[r] = lreg[r] * al + rs;
      o0[r] *= al;
      o1[r] *= al;
      pL[w][quad * 4 + r][li] = f2bf_u(p0);
      pL[w][quad * 4 + r][16 + li] = f2bf_u(p1);
    }
    __syncthreads();
    short8 pA  = *(const short8*)&pL[w][li][quad * 8];
    short8 vB0 = *(const short8*)&vT[buf][li][quad * 8];
    short8 vB1 = *(const short8*)&vT[buf][16 + li][quad * 8];
    o0 = __builtin_amdgcn_mfma_f32_16x16x32_bf16(pA, vB0, o0, 0, 0, 0);
    o1 = __builtin_amdgcn_mfma_f32_16x16x32_bf16(pA, vB1, o1, 0, 0, 0);
  }
#pragma unroll
  for (int r = 0; r < 4; ++r) {
    float inv = 1.0f / lreg[r];
    size_t row = (size_t)(qbase + quad * 4 + r);
    attno[row * C_ + h * 32 + li] = o0[r] * inv;
    attno[row * C_ + h * 32 + 16 + li] = o1[r] * inv;
  }
}

// ------------- attn out proj + LN2 -------------
__global__ void k_attnout(const float* __restrict__ attno, const float* __restrict__ x,
                          const float* __restrict__ w, const float* __restrict__ b,
                          const float* __restrict__ g, const float* __restrict__ bln,
                          float* __restrict__ ha) {
  __shared__ float inL[4][C_];
  __shared__ float red[C_];
  int t = threadIdx.x;
  int row0 = blockIdx.x * 4;
  float xv[4];
#pragma unroll
  for (int r = 0; r < 4; ++r) {
    size_t idx = (size_t)(row0 + r) * C_ + t;
    inL[r][t] = attno[idx];
    xv[r] = x[idx];
  }
  __syncthreads();
  float acc[4];
  float bb = b[t];
#pragma unroll
  for (int r = 0; r < 4; ++r) acc[r] = bb;
  for (int k = 0; k < C_; ++k) {
    float wv = w[k * C_ + t];
#pragma unroll
    for (int r = 0; r < 4; ++r) acc[r] += inL[r][k] * wv;
  }
  float gg = g[t], bl = bln[t];
  for (int r = 0; r < 4; ++r) {
    float v = acc[r] + xv[r];
    float mu = block_sum128(v, red, t) * (1.0f / C_);
    float d = v - mu;
    float var = block_sum128(d * d, red, t) * (1.0f / C_);
    ha[(size_t)(row0 + r) * C_ + t] = d * rsqrtf(var + LNE) * gg + bl;
  }
}

// ------------- FFN -------------
__global__ void k_ffn(const float* __restrict__ hl, const float* __restrict__ ha,
                      float* __restrict__ x,
                      const float* __restrict__ w1, const float* __restrict__ b1,
                      const float* __restrict__ w2, const float* __restrict__ b2,
                      const float* __restrict__ g, const float* __restrict__ bln) {
  __shared__ float outL[4][C_];
  __shared__ float hidL[4][2 * C_];
  __shared__ float red[C_];
  int t = threadIdx.x;
  int row0 = blockIdx.x * 4;
  float outv[4];
#pragma unroll
  for (int r = 0; r < 4; ++r) {
    size_t idx = (size_t)(row0 + r) * C_ + t;
    float v = hl[idx] + ha[idx];
    outv[r] = v;
    outL[r][t] = v;
  }
  __syncthreads();
  float acc2[4][2];
  float ba = b1[t], bbv = b1[t + 128];
#pragma unroll
  for (int r = 0; r < 4; ++r) { acc2[r][0] = ba; acc2[r][1] = bbv; }
  for (int k = 0; k < C_; ++k) {
    float wa = w1[k * 256 + t];
    float wb = w1[k * 256 + t + 128];
#pragma unroll
    for (int r = 0; r < 4; ++r) {
      float iv = outL[r][k];
      acc2[r][0] += iv * wa;
      acc2[r][1] += iv * wb;
    }
  }
#pragma unroll
  for (int r = 0; r < 4; ++r) {
    hidL[r][t] = gelu_tanh(acc2[r][0]);
    hidL[r][t + 128] = gelu_tanh(acc2[r][1]);
  }
  __syncthreads();
  float acc[4];
  float b2v = b2[t];
#pragma unroll
  for (int r = 0; r < 4; ++r) acc[r] = b2v;
  for (int k = 0; k < 2 * C_; ++k) {
    float wv = w2[k * C_ + t];
#pragma unroll
    for (int r = 0; r < 4; ++r) acc[r] += hidL[r][k] * wv;
  }
  float gg = g[t], bl = bln[t];
  for (int r = 0; r < 4; ++r) {
    float v = outv[r] + acc[r];
    float mu = block_sum128(v, red, t) * (1.0f / C_);
    float d = v - mu;
    float var = block_sum128(d * d, red, t) * (1.0f / C_);
    size_t idx = (size_t)(row0 + r) * C_ + t;
    x[idx] = x[idx] + d * rsqrtf(var + LNE) * gg + bl;
  }
}

// ------------- post MLP -------------
__global__ void k_post(float* __restrict__ x,
                       const float* __restrict__ w1, const float* __restrict__ b1,
                       const float* __restrict__ w2, const float* __restrict__ b2) {
  __shared__ float inL[4][C_];
  __shared__ float hidL[4][C_];
  int t = threadIdx.x;
  int row0 = blockIdx.x * 4;
  float xv[4];
#pragma unroll
  for (int r = 0; r < 4; ++r) {
    size_t idx = (size_t)(row0 + r) * C_ + t;
    xv[r] = x[idx];
    inL[r][t] = xv[r];
  }
  __syncthreads();
  float acc[4];
  float bb = b1[t];
#pragma unroll
  for (int r = 0; r < 4; ++r) acc[r] = bb;
  for (int k = 0; k < C_; ++k) {
    float wv = w1[k * C_ + t];
#pragma unroll
    for (int r = 0; r < 4; ++r) acc[r] += inL[r][k] * wv;
  }
#pragma unroll
  for (int r = 0; r < 4; ++r) hidL[r][t] = fmaxf(acc[r], 0.0f);
  __syncthreads();
  float bb2 = b2[t];
#pragma unroll
  for (int r = 0; r < 4; ++r) acc[r] = bb2;
  for (int k = 0; k < C_; ++k) {
    float wv = w2[k * C_ + t];
#pragma unroll
    for (int r = 0; r < 4; ++r) acc[r] += hidL[r][k] * wv;
  }
#pragma unroll
  for (int r = 0; r < 4; ++r) {
    size_t idx = (size_t)(row0 + r) * C_ + t;
    x[idx] = xv[r] + acc[r];
  }
}

// ------------- mean pool per graph -------------
__global__ void k_pool(const float* __restrict__ x, float* __restrict__ gmean) {
  int t = threadIdx.x;
  int b = blockIdx.x;
  float s = 0.0f;
  for (int sidx = 0; sidx < S_; ++sidx) s += x[((size_t)b * S_ + sidx) * C_ + t];
  gmean[b * C_ + t] = s * (1.0f / S_);
}

// ------------- readout -------------
__global__ void k_readout(const float* __restrict__ gmean,
                          const float* __restrict__ w1, const float* __restrict__ b1,
                          const float* __restrict__ w2, const float* __restrict__ b2,
                          float* __restrict__ out) {
  __shared__ float gL[C_];
  __shared__ float red[C_];
  int t = threadIdx.x;
  int b = blockIdx.x;
  gL[t] = gmean[b * C_ + t];
  __syncthreads();
  float acc = b1[t];
  for (int k = 0; k < C_; ++k) acc += gL[k] * w1[k * C_ + t];
  float hid = fmaxf(acc, 0.0f);
  float part = hid * w2[t];
  float tot = block_sum128(part, red, t);
  if (t == 0) out[b] = tot + b2[0];
}

}  // namespace

extern "C" void kernel_launch(void* const* d_in, const int* in_sizes, int n_in,
                              void* d_out, int out_size, void* d_ws, size_t ws_size,
                              hipStream_t stream) {
  const float* in_x      = (const float*)d_in[0];
  const int*   edge_idx  = (const int*)d_in[1];
  const float* edge_attr = (const float*)d_in[3];
  const float* lap_pe    = (const float*)d_in[4];
  const float* node_w1 = (const float*)d_in[5];
  const float* node_b1 = (const float*)d_in[6];
  const float* node_w2 = (const float*)d_in[7];
  const float* node_b2 = (const float*)d_in[8];
  const float* edge_w1 = (const float*)d_in[9];
  const float* edge_b1 = (const float*)d_in[10];
  const float* edge_w2 = (const float*)d_in[11];
  const float* edge_b2 = (const float*)d_in[12];
  const float* eps     = (const float*)d_in[13];
  const float* gin_w1  = (const float*)d_in[14];
  const float* gin_b1  = (const float*)d_in[15];
  const float* gin_w2  = (const float*)d_in[16];
  const float* gin_b2  = (const float*)d_in[17];
  const float* elin_w  = (const float*)d_in[18];
  const float* elin_b  = (const float*)d_in[19];
  const float* aqkv_w  = (const float*)d_in[20];
  const float* aqkv_b  = (const float*)d_in[21];
  const float* aout_w  = (const float*)d_in[22];
  const float* aout_b  = (const float*)d_in[23];
  const float* mlp_w1  = (const float*)d_in[24];
  const float* mlp_b1  = (const float*)d_in[25];
  const float* mlp_w2  = (const float*)d_in[26];
  const float* mlp_b2  = (const float*)d_in[27];
  const float* ln1_g   = (const float*)d_in[28];
  const float* ln1_b   = (const float*)d_in[29];
  const float* ln2_g   = (const float*)d_in[30];
  const float* ln2_b   = (const float*)d_in[31];
  const float* ln3_g   = (const float*)d_in[32];
  const float* ln3_b   = (const float*)d_in[33];
  const float* post_w1 = (const float*)d_in[34];
  const float* post_b1 = (const float*)d_in[35];
  const float* post_w2 = (const float*)d_in[36];
  const float* post_b2 = (const float*)d_in[37];
  const float* ro_w1   = (const float*)d_in[38];
  const float* ro_b1   = (const float*)d_in[39];
  const float* ro_w2   = (const float*)d_in[40];
  const float* ro_b2   = (const float*)d_in[41];

  const int* src = edge_idx;
  const int* dst = edge_idx + E_;

  float* ws = (float*)d_ws;
  float* x     = ws;                          // N*C
  float* qkv   = x + (size_t)N_ * C_;         // 3*N*C float region; used as bf16 [N][384]
  float* agg   = qkv;                         // aliases qkv[0 : N*C] (disjoint lifetimes)
  float* hl    = qkv + (size_t)N_ * 3 * C_;   // N*C
  float* attno = hl + (size_t)N_ * C_;        // N*C
  float* ha    = attno;                       // in-place
  float* fw2   = attno + (size_t)N_ * C_;     // L*C*C
  float* fb2   = fw2 + (size_t)4 * C_ * C_;   // L*C
  float* gmean = hl;                          // alias (hl dead after last ffn)
  unsigned short* qkvb = (unsigned short*)qkv;

  float* out = (float*)d_out;

  dim3 blk(128);

  k_fuse_w<<<4 * (C_ + 1), blk, 0, stream>>>(edge_w2, edge_b2, elin_w, elin_b, fw2, fb2);
  k_node_enc<<<N_ / 4, blk, 0, stream>>>(in_x, lap_pe, node_w1, node_b1, node_w2, node_b2, x);

  for (int i = 0; i < 4; ++i) {
    k_zero<<<(N_ * C_ / 4 + 255) / 256, 256, 0, stream>>>((float4*)agg, N_ * C_ / 4);
    k_edge_layer<<<E_ / 8, blk, 0, stream>>>(edge_attr, x, src, dst,
                                             edge_w1, edge_b1,
                                             fw2 + (size_t)i * C_ * C_, fb2 + i * C_, agg);
    k_gin<<<N_ / 4, blk, 0, stream>>>(x, agg,
                                      gin_w1 + (size_t)i * C_ * C_, gin_b1 + i * C_,
                                      gin_w2 + (size_t)i * C_ * C_, gin_b2 + i * C_,
                                      ln1_g + i * C_, ln1_b + i * C_, eps, i, hl);
    k_qkv<<<N_ / 4, blk, 0, stream>>>(x, aqkv_w + (size_t)i * C_ * 384, aqkv_b + i * 384, qkvb);
    k_attn_mfma<<<B_ * 4 * 16, 256, 0, stream>>>(qkvb, attno);
    k_attnout<<<N_ / 4, blk, 0, stream>>>(attno, x,
                                          aout_w + (size_t)i * C_ * C_, aout_b + i * C_,
                                          ln2_g + i * C_, ln2_b + i * C_, ha);
    k_ffn<<<N_ / 4, blk, 0, stream>>>(hl, ha, x,
                                      mlp_w1 + (size_t)i * C_ * 256, mlp_b1 + i * 256,
                                      mlp_w2 + (size_t)i * 256 * C_, mlp_b2 + i * C_,
                                      ln3_g + i * C_, ln3_b + i * C_);
  }

  k_post<<<N_ / 4, blk, 0, stream>>>(x, post_w1, post_b1, post_w2, post_b2);
  k_pool<<<B_, blk, 0, stream>>>(x, gmean);
  k_readout<<<B_, blk, 0, stream>>>(gmean, ro_w1, ro_b1, ro_w2, ro_b2, out);
}

// Round 4
// 2672.685 us; speedup vs baseline: 1.8365x; 1.0331x over previous
//
#include <hip/hip_runtime.h>
#include <math.h>

namespace {

constexpr int N_  = 32768;   // nodes
constexpr int S_  = 1024;    // nodes per graph
constexpr int B_  = 32;      // graphs
constexpr int E_  = 262144;  // edges
constexpr int C_  = 128;     // hidden
constexpr int ND_ = 64;
constexpr int PE_ = 16;
constexpr int ED_ = 16;
constexpr float LNE = 1e-5f;

typedef __attribute__((ext_vector_type(8))) short short8;
typedef __attribute__((ext_vector_type(4))) float floatx4;

__device__ inline float gelu_tanh(float v) {
  const float c = 0.7978845608028654f;
  return 0.5f * v * (1.0f + tanhf(c * (v + 0.044715f * v * v * v)));
}

__device__ inline unsigned short f2bf_u(float f) {
  unsigned u = __float_as_uint(f);
  u += 0x7fff + ((u >> 16) & 1);
  return (unsigned short)(u >> 16);
}

// block of 128 threads: sum of v across all threads
__device__ inline float block_sum128(float v, float* red, int t) {
  red[t] = v;
  __syncthreads();
#pragma unroll
  for (int off = 64; off > 0; off >>= 1) {
    if (t < off) red[t] += red[t + off];
    __syncthreads();
  }
  float r = red[0];
  __syncthreads();
  return r;
}

// ---------------- zero a float buffer (graph-capture-safe memset) ----------------
__global__ void k_zero(float4* __restrict__ p, int n4) {
  int i = blockIdx.x * 256 + threadIdx.x;
  if (i < n4) p[i] = make_float4(0.f, 0.f, 0.f, 0.f);
}

// ---------------- fold edge_w2 into elin; emit TRANSPOSED bf16 weight ----------------
// fw2[l][k][n] = sum_m edge_w2[k][m] * elin_w[l][m][n];  fw2t[l][n][k] = bf16(fw2[l][k][n])
// fb2[l][n] = elin_b[l][n] + sum_m edge_b2[m] * elin_w[l][m][n]
__global__ void k_fuse_w(const float* __restrict__ w2, const float* __restrict__ b2,
                         const float* __restrict__ elin_w, const float* __restrict__ elin_b,
                         unsigned short* __restrict__ fw2t, float* __restrict__ fb2) {
  int t = threadIdx.x;
  int bid = blockIdx.x;
  int layer = bid / (C_ + 1);
  int k = bid % (C_ + 1);
  const float* el = elin_w + (size_t)layer * C_ * C_;
  if (k < C_) {
    float a = 0.0f;
    for (int m = 0; m < C_; ++m) a += w2[k * C_ + m] * el[m * C_ + t];
    fw2t[(size_t)layer * C_ * C_ + t * C_ + k] = f2bf_u(a);
  } else {
    float a = elin_b[layer * C_ + t];
    for (int m = 0; m < C_; ++m) a += b2[m] * el[m * C_ + t];
    fb2[layer * C_ + t] = a;
  }
}

// ---------------- node encoder ----------------
__global__ void k_node_enc(const float* __restrict__ xin, const float* __restrict__ pe,
                           const float* __restrict__ w1, const float* __restrict__ b1,
                           const float* __restrict__ w2, const float* __restrict__ b2,
                           float* __restrict__ xout) {
  __shared__ float inL[4][80];
  __shared__ float hidL[4][C_];
  int t = threadIdx.x;
  int row0 = blockIdx.x * 4;
#pragma unroll
  for (int r = 0; r < 4; ++r) {
    int row = row0 + r;
    if (t < ND_) inL[r][t] = xin[(size_t)row * ND_ + t];
    else if (t < 80) inL[r][t] = pe[(size_t)row * PE_ + (t - ND_)];
  }
  __syncthreads();
  float acc[4];
  float bb = b1[t];
#pragma unroll
  for (int r = 0; r < 4; ++r) acc[r] = bb;
  for (int k = 0; k < 80; ++k) {
    float wv = w1[k * C_ + t];
#pragma unroll
    for (int r = 0; r < 4; ++r) acc[r] += inL[r][k] * wv;
  }
#pragma unroll
  for (int r = 0; r < 4; ++r) hidL[r][t] = fmaxf(acc[r], 0.0f);
  __syncthreads();
  float bb2 = b2[t];
#pragma unroll
  for (int r = 0; r < 4; ++r) acc[r] = bb2;
  for (int k = 0; k < C_; ++k) {
    float wv = w2[k * C_ + t];
#pragma unroll
    for (int r = 0; r < 4; ++r) acc[r] += hidL[r][k] * wv;
  }
#pragma unroll
  for (int r = 0; r < 4; ++r) xout[(size_t)(row0 + r) * C_ + t] = acc[r];
}

// ------------- MFMA fused edge pipeline -------------
// Block: 256 thr (4 waves), 64 edges. Stage1: hidden[64][128] = relu(ea@ew1+eb1) in bf16 LDS
// (pitch 136). Stage2: per wave 16 edges, acc = hidden @ fw2t (MFMA 16x16x32, B-frags are
// contiguous dwordx4 from the 32KB L1-resident transposed weight). Epilogue: +fb2 +x[src],
// relu, atomicAdd to agg[dst].
__global__ __launch_bounds__(256) void k_edge_mfma(
    const float* __restrict__ ea, const float* __restrict__ x,
    const int* __restrict__ src, const int* __restrict__ dst,
    const float* __restrict__ ew1, const float* __restrict__ eb1,
    const unsigned short* __restrict__ fw2t, const float* __restrict__ fb2,
    float* __restrict__ agg) {
  __shared__ float eaL[64][ED_];            // 4 KB
  __shared__ unsigned short hid[64][136];   // 17.4 KB, pitch 136 for b128 bank spread
  int tid = threadIdx.x;
  int e0 = blockIdx.x * 64;

  // stage ea: 64 rows x 4 float4 = 256 float4, one per thread
  {
    int r = tid >> 2, c4 = tid & 3;
    ((float4*)&eaL[r][0])[c4] = ((const float4*)(ea + (size_t)(e0 + r) * ED_))[c4];
  }
  __syncthreads();

  // hidden: thread -> col = tid&127, rows (tid>>7)*32 .. +32 ; K=16
  {
    int col = tid & 127;
    int rh = (tid >> 7) * 32;
    float acch[32];
    float bb = eb1[col];
#pragma unroll
    for (int rr = 0; rr < 32; ++rr) acch[rr] = bb;
    for (int k = 0; k < ED_; ++k) {
      float wv = ew1[k * C_ + col];
#pragma unroll
      for (int rr = 0; rr < 32; ++rr) acch[rr] += eaL[rh + rr][k] * wv;
    }
#pragma unroll
    for (int rr = 0; rr < 32; ++rr) hid[rh + rr][col] = f2bf_u(fmaxf(acch[rr], 0.0f));
  }
  __syncthreads();

  int lane = tid & 63;
  int w = tid >> 6;
  int li = lane & 15;
  int quad = lane >> 4;
  int r0 = w * 16;

  short8 aK[4];
#pragma unroll
  for (int k4 = 0; k4 < 4; ++k4)
    aK[k4] = *(const short8*)&hid[r0 + li][k4 * 32 + quad * 8];

  floatx4 acc[8];
#pragma unroll
  for (int t8 = 0; t8 < 8; ++t8) acc[t8] = (floatx4){0.f, 0.f, 0.f, 0.f};

#pragma unroll
  for (int t8 = 0; t8 < 8; ++t8) {
    int n = t8 * 16 + li;
    const unsigned short* bp = fw2t + (size_t)n * C_ + quad * 8;
#pragma unroll
    for (int k4 = 0; k4 < 4; ++k4) {
      short8 bf = *(const short8*)(bp + k4 * 32);
      acc[t8] = __builtin_amdgcn_mfma_f32_16x16x32_bf16(aK[k4], bf, acc[t8], 0, 0, 0);
    }
  }

  float fbv[8];
#pragma unroll
  for (int t8 = 0; t8 < 8; ++t8) fbv[t8] = fb2[t8 * 16 + li];

#pragma unroll
  for (int reg = 0; reg < 4; ++reg) {
    int ed = e0 + r0 + quad * 4 + reg;
    const float* xs = x + (size_t)src[ed] * C_;
    float* ag = agg + (size_t)dst[ed] * C_;
#pragma unroll
    for (int t8 = 0; t8 < 8; ++t8) {
      int n = t8 * 16 + li;
      float v = acc[t8][reg] + fbv[t8] + xs[n];
      v = fmaxf(v, 0.0f);
      atomicAdd(&ag[n], v);
    }
  }
}

// ------------- GIN -------------
__global__ void k_gin(const float* __restrict__ x, const float* __restrict__ agg,
                      const float* __restrict__ w1, const float* __restrict__ b1,
                      const float* __restrict__ w2, const float* __restrict__ b2,
                      const float* __restrict__ g, const float* __restrict__ bln,
                      const float* __restrict__ epsarr, int layer,
                      float* __restrict__ hl) {
  __shared__ float inL[4][C_];
  __shared__ float hidL[4][C_];
  __shared__ float red[C_];
  int t = threadIdx.x;
  int row0 = blockIdx.x * 4;
  float epsv = 1.0f + epsarr[layer];
  float xv[4];
#pragma unroll
  for (int r = 0; r < 4; ++r) {
    size_t idx = (size_t)(row0 + r) * C_ + t;
    float xx = x[idx];
    xv[r] = xx;
    inL[r][t] = epsv * xx + agg[idx];
  }
  __syncthreads();
  float acc[4];
  float bb = b1[t];
#pragma unroll
  for (int r = 0; r < 4; ++r) acc[r] = bb;
  for (int k = 0; k < C_; ++k) {
    float wv = w1[k * C_ + t];
#pragma unroll
    for (int r = 0; r < 4; ++r) acc[r] += inL[r][k] * wv;
  }
#pragma unroll
  for (int r = 0; r < 4; ++r) hidL[r][t] = fmaxf(acc[r], 0.0f);
  __syncthreads();
  float bb2 = b2[t];
#pragma unroll
  for (int r = 0; r < 4; ++r) acc[r] = bb2;
  for (int k = 0; k < C_; ++k) {
    float wv = w2[k * C_ + t];
#pragma unroll
    for (int r = 0; r < 4; ++r) acc[r] += hidL[r][k] * wv;
  }
  float gg = g[t], bl = bln[t];
  for (int r = 0; r < 4; ++r) {
    float v = acc[r] + xv[r];
    float mu = block_sum128(v, red, t) * (1.0f / C_);
    float d = v - mu;
    float var = block_sum128(d * d, red, t) * (1.0f / C_);
    hl[(size_t)(row0 + r) * C_ + t] = d * rsqrtf(var + LNE) * gg + bl;
  }
}

// ------------- QKV projection -> bf16 qkv -------------
__global__ void k_qkv(const float* __restrict__ x,
                      const float* __restrict__ w, const float* __restrict__ b,
                      unsigned short* __restrict__ qkvb) {
  __shared__ float inL[4][C_];
  int t = threadIdx.x;
  int row0 = blockIdx.x * 4;
#pragma unroll
  for (int r = 0; r < 4; ++r) inL[r][t] = x[(size_t)(row0 + r) * C_ + t];
  __syncthreads();
  float acc[4][3];
  float b0 = b[t], b1v = b[t + 128], b2v = b[t + 256];
#pragma unroll
  for (int r = 0; r < 4; ++r) { acc[r][0] = b0; acc[r][1] = b1v; acc[r][2] = b2v; }
  for (int k = 0; k < C_; ++k) {
    float w0 = w[k * 384 + t];
    float w1v = w[k * 384 + t + 128];
    float w2v = w[k * 384 + t + 256];
#pragma unroll
    for (int r = 0; r < 4; ++r) {
      float iv = inL[r][k];
      acc[r][0] += iv * w0;
      acc[r][1] += iv * w1v;
      acc[r][2] += iv * w2v;
    }
  }
#pragma unroll
  for (int r = 0; r < 4; ++r) {
    size_t base = (size_t)(row0 + r) * 384;
    qkvb[base + t]       = f2bf_u(acc[r][0]);
    qkvb[base + t + 128] = f2bf_u(acc[r][1]);
    qkvb[base + t + 256] = f2bf_u(acc[r][2]);
  }
}

// ------------- MFMA flash attention -------------
__global__ __launch_bounds__(256) void k_attn_mfma(const unsigned short* __restrict__ qkvb,
                                                   float* __restrict__ attno) {
  __shared__ unsigned short kL[2][32][40];
  __shared__ unsigned short vT[2][32][40];
  __shared__ unsigned short pL[4][16][40];
  int tid = threadIdx.x;
  int lane = tid & 63;
  int w = tid >> 6;
  int li = lane & 15;
  int quad = lane >> 4;
  int bid = blockIdx.x;
  int qt = bid & 15;
  int h = (bid >> 4) & 3;
  int b = bid >> 6;
  int qbase = b * S_ + qt * 64 + w * 16;

  short8 qA = *(const short8*)(qkvb + (size_t)(qbase + li) * 384 + h * 32 + quad * 8);

  floatx4 o0 = {0.f, 0.f, 0.f, 0.f}, o1 = {0.f, 0.f, 0.f, 0.f};
  float mreg[4] = {-1e30f, -1e30f, -1e30f, -1e30f};
  float lreg[4] = {0.f, 0.f, 0.f, 0.f};
  const float scale = 0.17677669529663687f;

  int half = tid >> 7;
  int tt = tid & 127;
  int j = tt >> 2;
  int seg = tt & 3;

  for (int kc = 0; kc < 32; ++kc) {
    int buf = kc & 1;
    {
      int node = b * S_ + kc * 32 + j;
      const unsigned short* p = qkvb + (size_t)node * 384 + (half ? 256 : 128) + h * 32 + seg * 8;
      short8 val = *(const short8*)p;
      if (half == 0) {
        *(short8*)&kL[buf][j][seg * 8] = val;
      } else {
#pragma unroll
        for (int i = 0; i < 8; ++i) vT[buf][seg * 8 + i][j] = (unsigned short)val[i];
      }
    }
    __syncthreads();
    short8 kB0 = *(const short8*)&kL[buf][li][quad * 8];
    short8 kB1 = *(const short8*)&kL[buf][16 + li][quad * 8];
    floatx4 z = {0.f, 0.f, 0.f, 0.f};
    floatx4 s0 = __builtin_amdgcn_mfma_f32_16x16x32_bf16(qA, kB0, z, 0, 0, 0);
    floatx4 s1 = __builtin_amdgcn_mfma_f32_16x16x32_bf16(qA, kB1, z, 0, 0, 0);
#pragma unroll
    for (int r = 0; r < 4; ++r) {
      float a0 = s0[r] * scale, a1 = s1[r] * scale;
      float cm = fmaxf(a0, a1);
#pragma unroll
      for (int msk = 1; msk <= 8; msk <<= 1) cm = fmaxf(cm, __shfl_xor(cm, msk));
      float mn = fmaxf(mreg[r], cm);
      float al = __expf(mreg[r] - mn);
      mreg[r] = mn;
      float p0 = __expf(a0 - mn), p1 = __expf(a1 - mn);
      float rs = p0 + p1;
#pragma unroll
      for (int msk = 1; msk <= 8; msk <<= 1) rs += __shfl_xor(rs, msk);
      lreg[r] = lreg[r] * al + rs;
      o0[r] *= al;
      o1[r] *= al;
      pL[w][quad * 4 + r][li] = f2bf_u(p0);
      pL[w][quad * 4 + r][16 + li] = f2bf_u(p1);
    }
    __syncthreads();
    short8 pA  = *(const short8*)&pL[w][li][quad * 8];
    short8 vB0 = *(const short8*)&vT[buf][li][quad * 8];
    short8 vB1 = *(const short8*)&vT[buf][16 + li][quad * 8];
    o0 = __builtin_amdgcn_mfma_f32_16x16x32_bf16(pA, vB0, o0, 0, 0, 0);
    o1 = __builtin_amdgcn_mfma_f32_16x16x32_bf16(pA, vB1, o1, 0, 0, 0);
  }
#pragma unroll
  for (int r = 0; r < 4; ++r) {
    float inv = 1.0f / lreg[r];
    size_t row = (size_t)(qbase + quad * 4 + r);
    attno[row * C_ + h * 32 + li] = o0[r] * inv;
    attno[row * C_ + h * 32 + 16 + li] = o1[r] * inv;
  }
}

// ------------- attn out proj + LN2 -------------
__global__ void k_attnout(const float* __restrict__ attno, const float* __restrict__ x,
                          const float* __restrict__ w, const float* __restrict__ b,
                          const float* __restrict__ g, const float* __restrict__ bln,
                          float* __restrict__ ha) {
  __shared__ float inL[4][C_];
  __shared__ float red[C_];
  int t = threadIdx.x;
  int row0 = blockIdx.x * 4;
  float xv[4];
#pragma unroll
  for (int r = 0; r < 4; ++r) {
    size_t idx = (size_t)(row0 + r) * C_ + t;
    inL[r][t] = attno[idx];
    xv[r] = x[idx];
  }
  __syncthreads();
  float acc[4];
  float bb = b[t];
#pragma unroll
  for (int r = 0; r < 4; ++r) acc[r] = bb;
  for (int k = 0; k < C_; ++k) {
    float wv = w[k * C_ + t];
#pragma unroll
    for (int r = 0; r < 4; ++r) acc[r] += inL[r][k] * wv;
  }
  float gg = g[t], bl = bln[t];
  for (int r = 0; r < 4; ++r) {
    float v = acc[r] + xv[r];
    float mu = block_sum128(v, red, t) * (1.0f / C_);
    float d = v - mu;
    float var = block_sum128(d * d, red, t) * (1.0f / C_);
    ha[(size_t)(row0 + r) * C_ + t] = d * rsqrtf(var + LNE) * gg + bl;
  }
}

// ------------- FFN -------------
__global__ void k_ffn(const float* __restrict__ hl, const float* __restrict__ ha,
                      float* __restrict__ x,
                      const float* __restrict__ w1, const float* __restrict__ b1,
                      const float* __restrict__ w2, const float* __restrict__ b2,
                      const float* __restrict__ g, const float* __restrict__ bln) {
  __shared__ float outL[4][C_];
  __shared__ float hidL[4][2 * C_];
  __shared__ float red[C_];
  int t = threadIdx.x;
  int row0 = blockIdx.x * 4;
  float outv[4];
#pragma unroll
  for (int r = 0; r < 4; ++r) {
    size_t idx = (size_t)(row0 + r) * C_ + t;
    float v = hl[idx] + ha[idx];
    outv[r] = v;
    outL[r][t] = v;
  }
  __syncthreads();
  float acc2[4][2];
  float ba = b1[t], bbv = b1[t + 128];
#pragma unroll
  for (int r = 0; r < 4; ++r) { acc2[r][0] = ba; acc2[r][1] = bbv; }
  for (int k = 0; k < C_; ++k) {
    float wa = w1[k * 256 + t];
    float wb = w1[k * 256 + t + 128];
#pragma unroll
    for (int r = 0; r < 4; ++r) {
      float iv = outL[r][k];
      acc2[r][0] += iv * wa;
      acc2[r][1] += iv * wb;
    }
  }
#pragma unroll
  for (int r = 0; r < 4; ++r) {
    hidL[r][t] = gelu_tanh(acc2[r][0]);
    hidL[r][t + 128] = gelu_tanh(acc2[r][1]);
  }
  __syncthreads();
  float acc[4];
  float b2v = b2[t];
#pragma unroll
  for (int r = 0; r < 4; ++r) acc[r] = b2v;
  for (int k = 0; k < 2 * C_; ++k) {
    float wv = w2[k * C_ + t];
#pragma unroll
    for (int r = 0; r < 4; ++r) acc[r] += hidL[r][k] * wv;
  }
  float gg = g[t], bl = bln[t];
  for (int r = 0; r < 4; ++r) {
    float v = outv[r] + acc[r];
    float mu = block_sum128(v, red, t) * (1.0f / C_);
    float d = v - mu;
    float var = block_sum128(d * d, red, t) * (1.0f / C_);
    size_t idx = (size_t)(row0 + r) * C_ + t;
    x[idx] = x[idx] + d * rsqrtf(var + LNE) * gg + bl;
  }
}

// ------------- post MLP -------------
__global__ void k_post(float* __restrict__ x,
                       const float* __restrict__ w1, const float* __restrict__ b1,
                       const float* __restrict__ w2, const float* __restrict__ b2) {
  __shared__ float inL[4][C_];
  __shared__ float hidL[4][C_];
  int t = threadIdx.x;
  int row0 = blockIdx.x * 4;
  float xv[4];
#pragma unroll
  for (int r = 0; r < 4; ++r) {
    size_t idx = (size_t)(row0 + r) * C_ + t;
    xv[r] = x[idx];
    inL[r][t] = xv[r];
  }
  __syncthreads();
  float acc[4];
  float bb = b1[t];
#pragma unroll
  for (int r = 0; r < 4; ++r) acc[r] = bb;
  for (int k = 0; k < C_; ++k) {
    float wv = w1[k * C_ + t];
#pragma unroll
    for (int r = 0; r < 4; ++r) acc[r] += inL[r][k] * wv;
  }
#pragma unroll
  for (int r = 0; r < 4; ++r) hidL[r][t] = fmaxf(acc[r], 0.0f);
  __syncthreads();
  float bb2 = b2[t];
#pragma unroll
  for (int r = 0; r < 4; ++r) acc[r] = bb2;
  for (int k = 0; k < C_; ++k) {
    float wv = w2[k * C_ + t];
#pragma unroll
    for (int r = 0; r < 4; ++r) acc[r] += hidL[r][k] * wv;
  }
#pragma unroll
  for (int r = 0; r < 4; ++r) {
    size_t idx = (size_t)(row0 + r) * C_ + t;
    x[idx] = xv[r] + acc[r];
  }
}

// ------------- mean pool per graph -------------
__global__ void k_pool(const float* __restrict__ x, float* __restrict__ gmean) {
  int t = threadIdx.x;
  int b = blockIdx.x;
  float s = 0.0f;
  for (int sidx = 0; sidx < S_; ++sidx) s += x[((size_t)b * S_ + sidx) * C_ + t];
  gmean[b * C_ + t] = s * (1.0f / S_);
}

// ------------- readout -------------
__global__ void k_readout(const float* __restrict__ gmean,
                          const float* __restrict__ w1, const float* __restrict__ b1,
                          const float* __restrict__ w2, const float* __restrict__ b2,
                          float* __restrict__ out) {
  __shared__ float gL[C_];
  __shared__ float red[C_];
  int t = threadIdx.x;
  int b = blockIdx.x;
  gL[t] = gmean[b * C_ + t];
  __syncthreads();
  float acc = b1[t];
  for (int k = 0; k < C_; ++k) acc += gL[k] * w1[k * C_ + t];
  float hid = fmaxf(acc, 0.0f);
  float part = hid * w2[t];
  float tot = block_sum128(part, red, t);
  if (t == 0) out[b] = tot + b2[0];
}

}  // namespace

extern "C" void kernel_launch(void* const* d_in, const int* in_sizes, int n_in,
                              void* d_out, int out_size, void* d_ws, size_t ws_size,
                              hipStream_t stream) {
  const float* in_x      = (const float*)d_in[0];
  const int*   edge_idx  = (const int*)d_in[1];
  const float* edge_attr = (const float*)d_in[3];
  const float* lap_pe    = (const float*)d_in[4];
  const float* node_w1 = (const float*)d_in[5];
  const float* node_b1 = (const float*)d_in[6];
  const float* node_w2 = (const float*)d_in[7];
  const float* node_b2 = (const float*)d_in[8];
  const float* edge_w1 = (const float*)d_in[9];
  const float* edge_b1 = (const float*)d_in[10];
  const float* edge_w2 = (const float*)d_in[11];
  const float* edge_b2 = (const float*)d_in[12];
  const float* eps     = (const float*)d_in[13];
  const float* gin_w1  = (const float*)d_in[14];
  const float* gin_b1  = (const float*)d_in[15];
  const float* gin_w2  = (const float*)d_in[16];
  const float* gin_b2  = (const float*)d_in[17];
  const float* elin_w  = (const float*)d_in[18];
  const float* elin_b  = (const float*)d_in[19];
  const float* aqkv_w  = (const float*)d_in[20];
  const float* aqkv_b  = (const float*)d_in[21];
  const float* aout_w  = (const float*)d_in[22];
  const float* aout_b  = (const float*)d_in[23];
  const float* mlp_w1  = (const float*)d_in[24];
  const float* mlp_b1  = (const float*)d_in[25];
  const float* mlp_w2  = (const float*)d_in[26];
  const float* mlp_b2  = (const float*)d_in[27];
  const float* ln1_g   = (const float*)d_in[28];
  const float* ln1_b   = (const float*)d_in[29];
  const float* ln2_g   = (const float*)d_in[30];
  const float* ln2_b   = (const float*)d_in[31];
  const float* ln3_g   = (const float*)d_in[32];
  const float* ln3_b   = (const float*)d_in[33];
  const float* post_w1 = (const float*)d_in[34];
  const float* post_b1 = (const float*)d_in[35];
  const float* post_w2 = (const float*)d_in[36];
  const float* post_b2 = (const float*)d_in[37];
  const float* ro_w1   = (const float*)d_in[38];
  const float* ro_b1   = (const float*)d_in[39];
  const float* ro_w2   = (const float*)d_in[40];
  const float* ro_b2   = (const float*)d_in[41];

  const int* src = edge_idx;
  const int* dst = edge_idx + E_;

  float* ws = (float*)d_ws;
  float* x     = ws;                          // N*C
  float* qkv   = x + (size_t)N_ * C_;         // 3*N*C float region; bf16 [N][384] view
  float* agg   = qkv;                         // aliases qkv[0 : N*C] (disjoint lifetimes)
  float* hl    = qkv + (size_t)N_ * 3 * C_;   // N*C
  float* attno = hl + (size_t)N_ * C_;        // N*C
  float* ha    = attno;                       // in-place
  float* fb2   = attno + (size_t)N_ * C_;     // L*C floats
  unsigned short* fw2tb = (unsigned short*)(fb2 + 4 * C_);  // L*C*C bf16 (transposed [n][k])
  float* gmean = hl;                          // alias
  unsigned short* qkvb = (unsigned short*)qkv;

  float* out = (float*)d_out;

  dim3 blk(128);

  k_fuse_w<<<4 * (C_ + 1), blk, 0, stream>>>(edge_w2, edge_b2, elin_w, elin_b, fw2tb, fb2);
  k_node_enc<<<N_ / 4, blk, 0, stream>>>(in_x, lap_pe, node_w1, node_b1, node_w2, node_b2, x);

  for (int i = 0; i < 4; ++i) {
    k_zero<<<(N_ * C_ / 4 + 255) / 256, 256, 0, stream>>>((float4*)agg, N_ * C_ / 4);
    k_edge_mfma<<<E_ / 64, 256, 0, stream>>>(edge_attr, x, src, dst,
                                             edge_w1, edge_b1,
                                             fw2tb + (size_t)i * C_ * C_, fb2 + i * C_, agg);
    k_gin<<<N_ / 4, blk, 0, stream>>>(x, agg,
                                      gin_w1 + (size_t)i * C_ * C_, gin_b1 + i * C_,
                                      gin_w2 + (size_t)i * C_ * C_, gin_b2 + i * C_,
                                      ln1_g + i * C_, ln1_b + i * C_, eps, i, hl);
    k_qkv<<<N_ / 4, blk, 0, stream>>>(x, aqkv_w + (size_t)i * C_ * 384, aqkv_b + i * 384, qkvb);
    k_attn_mfma<<<B_ * 4 * 16, 256, 0, stream>>>(qkvb, attno);
    k_attnout<<<N_ / 4, blk, 0, stream>>>(attno, x,
                                          aout_w + (size_t)i * C_ * C_, aout_b + i * C_,
                                          ln2_g + i * C_, ln2_b + i * C_, ha);
    k_ffn<<<N_ / 4, blk, 0, stream>>>(hl, ha, x,
                                      mlp_w1 + (size_t)i * C_ * 256, mlp_b1 + i * 256,
                                      mlp_w2 + (size_t)i * 256 * C_, mlp_b2 + i * C_,
                                      ln3_g + i * C_, ln3_b + i * C_);
  }

  k_post<<<N_ / 4, blk, 0, stream>>>(x, post_w1, post_b1, post_w2, post_b2);
  k_pool<<<B_, blk, 0, stream>>>(x, gmean);
  k_readout<<<B_, blk, 0, stream>>>(gmean, ro_w1, ro_b1, ro_w2, ro_b2, out);
}

// Round 5
// 2086.354 us; speedup vs baseline: 2.3526x; 1.2810x over previous
//
#include <hip/hip_runtime.h>
#include <math.h>

namespace {

constexpr int N_  = 32768;   // nodes
constexpr int S_  = 1024;    // nodes per graph
constexpr int B_  = 32;      // graphs
constexpr int E_  = 262144;  // edges
constexpr int C_  = 128;     // hidden
constexpr int ND_ = 64;
constexpr int PE_ = 16;
constexpr int ED_ = 16;
constexpr float LNE = 1e-5f;

typedef __attribute__((ext_vector_type(8))) short short8;
typedef __attribute__((ext_vector_type(4))) float floatx4;

__device__ inline float gelu_tanh(float v) {
  const float c = 0.7978845608028654f;
  return 0.5f * v * (1.0f + tanhf(c * (v + 0.044715f * v * v * v)));
}

__device__ inline unsigned short f2bf_u(float f) {
  unsigned u = __float_as_uint(f);
  u += 0x7fff + ((u >> 16) & 1);
  return (unsigned short)(u >> 16);
}

__device__ inline float block_sum128(float v, float* red, int t) {
  red[t] = v;
  __syncthreads();
#pragma unroll
  for (int off = 64; off > 0; off >>= 1) {
    if (t < off) red[t] += red[t + off];
    __syncthreads();
  }
  float r = red[0];
  __syncthreads();
  return r;
}

// ---------------- zero (graph-capture-safe memset) ----------------
__global__ void k_zero(float4* __restrict__ p, int n4) {
  int i = blockIdx.x * 256 + threadIdx.x;
  if (i < n4) p[i] = make_float4(0.f, 0.f, 0.f, 0.f);
}

// ---------------- fold edge_w2 into elin; emit TRANSPOSED bf16 weight ----------------
__global__ void k_fuse_w(const float* __restrict__ w2, const float* __restrict__ b2,
                         const float* __restrict__ elin_w, const float* __restrict__ elin_b,
                         unsigned short* __restrict__ fw2t, float* __restrict__ fb2) {
  int t = threadIdx.x;
  int bid = blockIdx.x;
  int layer = bid / (C_ + 1);
  int k = bid % (C_ + 1);
  const float* el = elin_w + (size_t)layer * C_ * C_;
  if (k < C_) {
    float a = 0.0f;
    for (int m = 0; m < C_; ++m) a += w2[k * C_ + m] * el[m * C_ + t];
    fw2t[(size_t)layer * C_ * C_ + t * C_ + k] = f2bf_u(a);
  } else {
    float a = elin_b[layer * C_ + t];
    for (int m = 0; m < C_; ++m) a += b2[m] * el[m * C_ + t];
    fb2[layer * C_ + t] = a;
  }
}

// ---------------- prep: bf16-transpose all node-path weights ----------------
// Per layer (elem offsets, bf16):
//  0      gw1t [128][128]   gin_w1[k][n]  -> [n][k]
//  16384  gw2t [128][128]
//  32768  qkvt [384][128]   aqkv_w[k][n(384)]
//  81920  aot  [128][128]
//  98304  m1t  [256][128]   mlp_w1[k][n(256)]
//  131072 m2t  [128][256]   mlp_w2[k(256)][n]
//  layer stride 163840
__global__ void k_prep(const float* __restrict__ gin_w1, const float* __restrict__ gin_w2,
                       const float* __restrict__ aqkv_w, const float* __restrict__ aout_w,
                       const float* __restrict__ mlp_w1, const float* __restrict__ mlp_w2,
                       unsigned short* __restrict__ wt) {
  int t = threadIdx.x;
  int bid = blockIdx.x;
  int l = bid / 1152;
  int r = bid % 1152;
  unsigned short* base = wt + (size_t)l * 163840;
  if (r < 128) {
    base[r * 128 + t] = f2bf_u(gin_w1[(size_t)l * 16384 + t * 128 + r]);
  } else if (r < 256) {
    int n = r - 128;
    base[16384 + n * 128 + t] = f2bf_u(gin_w2[(size_t)l * 16384 + t * 128 + n]);
  } else if (r < 640) {
    int n = r - 256;
    base[32768 + n * 128 + t] = f2bf_u(aqkv_w[(size_t)l * 49152 + t * 384 + n]);
  } else if (r < 768) {
    int n = r - 640;
    base[81920 + n * 128 + t] = f2bf_u(aout_w[(size_t)l * 16384 + t * 128 + n]);
  } else if (r < 1024) {
    int n = r - 768;
    base[98304 + n * 128 + t] = f2bf_u(mlp_w1[(size_t)l * 32768 + t * 256 + n]);
  } else {
    int n = r - 1024;
    base[131072 + n * 256 + t]       = f2bf_u(mlp_w2[(size_t)l * 32768 + t * 128 + n]);
    base[131072 + n * 256 + 128 + t] = f2bf_u(mlp_w2[(size_t)l * 32768 + (t + 128) * 128 + n]);
  }
}

// ---------------- node encoder (scalar fp32) ----------------
__global__ void k_node_enc(const float* __restrict__ xin, const float* __restrict__ pe,
                           const float* __restrict__ w1, const float* __restrict__ b1,
                           const float* __restrict__ w2, const float* __restrict__ b2,
                           float* __restrict__ xout) {
  __shared__ float inL[4][80];
  __shared__ float hidL[4][C_];
  int t = threadIdx.x;
  int row0 = blockIdx.x * 4;
#pragma unroll
  for (int r = 0; r < 4; ++r) {
    int row = row0 + r;
    if (t < ND_) inL[r][t] = xin[(size_t)row * ND_ + t];
    else if (t < 80) inL[r][t] = pe[(size_t)row * PE_ + (t - ND_)];
  }
  __syncthreads();
  float acc[4];
  float bb = b1[t];
#pragma unroll
  for (int r = 0; r < 4; ++r) acc[r] = bb;
  for (int k = 0; k < 80; ++k) {
    float wv = w1[k * C_ + t];
#pragma unroll
    for (int r = 0; r < 4; ++r) acc[r] += inL[r][k] * wv;
  }
#pragma unroll
  for (int r = 0; r < 4; ++r) hidL[r][t] = fmaxf(acc[r], 0.0f);
  __syncthreads();
  float bb2 = b2[t];
#pragma unroll
  for (int r = 0; r < 4; ++r) acc[r] = bb2;
  for (int k = 0; k < C_; ++k) {
    float wv = w2[k * C_ + t];
#pragma unroll
    for (int r = 0; r < 4; ++r) acc[r] += hidL[r][k] * wv;
  }
#pragma unroll
  for (int r = 0; r < 4; ++r) xout[(size_t)(row0 + r) * C_ + t] = acc[r];
}

// ------------- MFMA fused edge pipeline (unchanged from r4; atomic-bound) -------------
__global__ __launch_bounds__(256) void k_edge_mfma(
    const float* __restrict__ ea, const float* __restrict__ x,
    const int* __restrict__ src, const int* __restrict__ dst,
    const float* __restrict__ ew1, const float* __restrict__ eb1,
    const unsigned short* __restrict__ fw2t, const float* __restrict__ fb2,
    float* __restrict__ agg) {
  __shared__ float eaL[64][ED_];
  __shared__ unsigned short hid[64][136];
  int tid = threadIdx.x;
  int e0 = blockIdx.x * 64;
  {
    int r = tid >> 2, c4 = tid & 3;
    ((float4*)&eaL[r][0])[c4] = ((const float4*)(ea + (size_t)(e0 + r) * ED_))[c4];
  }
  __syncthreads();
  {
    int col = tid & 127;
    int rh = (tid >> 7) * 32;
    float acch[32];
    float bb = eb1[col];
#pragma unroll
    for (int rr = 0; rr < 32; ++rr) acch[rr] = bb;
    for (int k = 0; k < ED_; ++k) {
      float wv = ew1[k * C_ + col];
#pragma unroll
      for (int rr = 0; rr < 32; ++rr) acch[rr] += eaL[rh + rr][k] * wv;
    }
#pragma unroll
    for (int rr = 0; rr < 32; ++rr) hid[rh + rr][col] = f2bf_u(fmaxf(acch[rr], 0.0f));
  }
  __syncthreads();

  int lane = tid & 63;
  int w = tid >> 6;
  int li = lane & 15;
  int quad = lane >> 4;
  int r0 = w * 16;

  short8 aK[4];
#pragma unroll
  for (int k4 = 0; k4 < 4; ++k4)
    aK[k4] = *(const short8*)&hid[r0 + li][k4 * 32 + quad * 8];

  floatx4 acc[8];
#pragma unroll
  for (int t8 = 0; t8 < 8; ++t8) acc[t8] = (floatx4){0.f, 0.f, 0.f, 0.f};

#pragma unroll
  for (int t8 = 0; t8 < 8; ++t8) {
    int n = t8 * 16 + li;
    const unsigned short* bp = fw2t + (size_t)n * C_ + quad * 8;
#pragma unroll
    for (int k4 = 0; k4 < 4; ++k4) {
      short8 bf = *(const short8*)(bp + k4 * 32);
      acc[t8] = __builtin_amdgcn_mfma_f32_16x16x32_bf16(aK[k4], bf, acc[t8], 0, 0, 0);
    }
  }

  float fbv[8];
#pragma unroll
  for (int t8 = 0; t8 < 8; ++t8) fbv[t8] = fb2[t8 * 16 + li];

#pragma unroll
  for (int reg = 0; reg < 4; ++reg) {
    int ed = e0 + r0 + quad * 4 + reg;
    const float* xs = x + (size_t)src[ed] * C_;
    float* ag = agg + (size_t)dst[ed] * C_;
#pragma unroll
    for (int t8 = 0; t8 < 8; ++t8) {
      int n = t8 * 16 + li;
      float v = acc[t8][reg] + fbv[t8] + xs[n];
      v = fmaxf(v, 0.0f);
      atomicAdd(&ag[n], v);
    }
  }
}

// ------------- MFMA GIN: hl = LN1(MLP2((1+eps)x + agg) + x) -------------
// 64 rows/block, 4 waves x 16 rows. LN fused via 16-lane shuffle reduce.
__global__ __launch_bounds__(256) void k_gin_mfma(
    const float* __restrict__ x, const float* __restrict__ agg,
    const unsigned short* __restrict__ w1t, const float* __restrict__ b1,
    const unsigned short* __restrict__ w2t, const float* __restrict__ b2,
    const float* __restrict__ g, const float* __restrict__ bln,
    const float* __restrict__ epsarr, int layer, float* __restrict__ hl) {
  __shared__ unsigned short inL[64][136];
  __shared__ unsigned short hidL[64][136];
  int tid = threadIdx.x;
  int row0 = blockIdx.x * 64;
  float epsv = 1.0f + epsarr[layer];
#pragma unroll
  for (int i = 0; i < 8; ++i) {
    int p = i * 256 + tid;
    int r = p >> 5, c4 = p & 31;
    float4 xa = *(const float4*)(x + (size_t)(row0 + r) * C_ + c4 * 4);
    float4 ag = *(const float4*)(agg + (size_t)(row0 + r) * C_ + c4 * 4);
    ushort4 u;
    u.x = f2bf_u(epsv * xa.x + ag.x);
    u.y = f2bf_u(epsv * xa.y + ag.y);
    u.z = f2bf_u(epsv * xa.z + ag.z);
    u.w = f2bf_u(epsv * xa.w + ag.w);
    *(ushort4*)&inL[r][c4 * 4] = u;
  }
  __syncthreads();
  int lane = tid & 63, w = tid >> 6, li = lane & 15, quad = lane >> 4;
  int r0 = w * 16;

  short8 aK[4];
#pragma unroll
  for (int k4 = 0; k4 < 4; ++k4) aK[k4] = *(const short8*)&inL[r0 + li][k4 * 32 + quad * 8];
  floatx4 acc[8];
#pragma unroll
  for (int t8 = 0; t8 < 8; ++t8) acc[t8] = (floatx4){0.f, 0.f, 0.f, 0.f};
#pragma unroll
  for (int t8 = 0; t8 < 8; ++t8) {
    const unsigned short* bp = w1t + (size_t)(t8 * 16 + li) * 128 + quad * 8;
#pragma unroll
    for (int k4 = 0; k4 < 4; ++k4) {
      short8 bf = *(const short8*)(bp + k4 * 32);
      acc[t8] = __builtin_amdgcn_mfma_f32_16x16x32_bf16(aK[k4], bf, acc[t8], 0, 0, 0);
    }
  }
  // bias + relu -> hidL (wave-private rows; same-wave LDS RAW is waitcnt-ordered)
#pragma unroll
  for (int t8 = 0; t8 < 8; ++t8) {
    float bv = b1[t8 * 16 + li];
#pragma unroll
    for (int reg = 0; reg < 4; ++reg)
      hidL[r0 + quad * 4 + reg][t8 * 16 + li] = f2bf_u(fmaxf(acc[t8][reg] + bv, 0.f));
  }
  short8 aK2[4];
#pragma unroll
  for (int k4 = 0; k4 < 4; ++k4) aK2[k4] = *(const short8*)&hidL[r0 + li][k4 * 32 + quad * 8];
  floatx4 acc2[8];
#pragma unroll
  for (int t8 = 0; t8 < 8; ++t8) acc2[t8] = (floatx4){0.f, 0.f, 0.f, 0.f};
#pragma unroll
  for (int t8 = 0; t8 < 8; ++t8) {
    const unsigned short* bp = w2t + (size_t)(t8 * 16 + li) * 128 + quad * 8;
#pragma unroll
    for (int k4 = 0; k4 < 4; ++k4) {
      short8 bf = *(const short8*)(bp + k4 * 32);
      acc2[t8] = __builtin_amdgcn_mfma_f32_16x16x32_bf16(aK2[k4], bf, acc2[t8], 0, 0, 0);
    }
  }
  float gv[8], blv[8], b2v[8];
#pragma unroll
  for (int t8 = 0; t8 < 8; ++t8) {
    int col = t8 * 16 + li;
    gv[t8] = g[col]; blv[t8] = bln[col]; b2v[t8] = b2[col];
  }
#pragma unroll
  for (int reg = 0; reg < 4; ++reg) {
    int row = row0 + r0 + quad * 4 + reg;
    float v[8], s = 0.f, s2 = 0.f;
#pragma unroll
    for (int t8 = 0; t8 < 8; ++t8) {
      float xv = x[(size_t)row * C_ + t8 * 16 + li];
      v[t8] = acc2[t8][reg] + b2v[t8] + xv;
      s += v[t8]; s2 += v[t8] * v[t8];
    }
#pragma unroll
    for (int m = 1; m <= 8; m <<= 1) { s += __shfl_xor(s, m); s2 += __shfl_xor(s2, m); }
    float mu = s * (1.0f / C_);
    float var = s2 * (1.0f / C_) - mu * mu;
    float inv = rsqrtf(var + LNE);
#pragma unroll
    for (int t8 = 0; t8 < 8; ++t8)
      hl[(size_t)row * C_ + t8 * 16 + li] = (v[t8] - mu) * inv * gv[t8] + blv[t8];
  }
}

// ------------- MFMA QKV: qkvb = bf16(x @ Wqkv + b) -------------
__global__ __launch_bounds__(256) void k_qkv_mfma(
    const float* __restrict__ x, const unsigned short* __restrict__ qkvt,
    const float* __restrict__ b, unsigned short* __restrict__ qkvb) {
  __shared__ unsigned short inL[64][136];
  int tid = threadIdx.x;
  int row0 = blockIdx.x * 64;
#pragma unroll
  for (int i = 0; i < 8; ++i) {
    int p = i * 256 + tid;
    int r = p >> 5, c4 = p & 31;
    float4 xa = *(const float4*)(x + (size_t)(row0 + r) * C_ + c4 * 4);
    ushort4 u;
    u.x = f2bf_u(xa.x); u.y = f2bf_u(xa.y); u.z = f2bf_u(xa.z); u.w = f2bf_u(xa.w);
    *(ushort4*)&inL[r][c4 * 4] = u;
  }
  __syncthreads();
  int lane = tid & 63, w = tid >> 6, li = lane & 15, quad = lane >> 4;
  int r0 = w * 16;
  short8 aK[4];
#pragma unroll
  for (int k4 = 0; k4 < 4; ++k4) aK[k4] = *(const short8*)&inL[r0 + li][k4 * 32 + quad * 8];
  floatx4 acc[24];
#pragma unroll
  for (int t8 = 0; t8 < 24; ++t8) acc[t8] = (floatx4){0.f, 0.f, 0.f, 0.f};
#pragma unroll
  for (int t8 = 0; t8 < 24; ++t8) {
    const unsigned short* bp = qkvt + (size_t)(t8 * 16 + li) * 128 + quad * 8;
#pragma unroll
    for (int k4 = 0; k4 < 4; ++k4) {
      short8 bf = *(const short8*)(bp + k4 * 32);
      acc[t8] = __builtin_amdgcn_mfma_f32_16x16x32_bf16(aK[k4], bf, acc[t8], 0, 0, 0);
    }
  }
#pragma unroll
  for (int t8 = 0; t8 < 24; ++t8) {
    int col = t8 * 16 + li;
    float bv = b[col];
#pragma unroll
    for (int reg = 0; reg < 4; ++reg) {
      int row = row0 + r0 + quad * 4 + reg;
      qkvb[(size_t)row * 384 + col] = f2bf_u(acc[t8][reg] + bv);
    }
  }
}

// ------------- MFMA flash attention (r3-verified) -------------
__global__ __launch_bounds__(256) void k_attn_mfma(const unsigned short* __restrict__ qkvb,
                                                   float* __restrict__ attno) {
  __shared__ unsigned short kL[2][32][40];
  __shared__ unsigned short vT[2][32][40];
  __shared__ unsigned short pL[4][16][40];
  int tid = threadIdx.x;
  int lane = tid & 63;
  int w = tid >> 6;
  int li = lane & 15;
  int quad = lane >> 4;
  int bid = blockIdx.x;
  int qt = bid & 15;
  int h = (bid >> 4) & 3;
  int b = bid >> 6;
  int qbase = b * S_ + qt * 64 + w * 16;

  short8 qA = *(const short8*)(qkvb + (size_t)(qbase + li) * 384 + h * 32 + quad * 8);

  floatx4 o0 = {0.f, 0.f, 0.f, 0.f}, o1 = {0.f, 0.f, 0.f, 0.f};
  float mreg[4] = {-1e30f, -1e30f, -1e30f, -1e30f};
  float lreg[4] = {0.f, 0.f, 0.f, 0.f};
  const float scale = 0.17677669529663687f;

  int half = tid >> 7;
  int tt = tid & 127;
  int j = tt >> 2;
  int seg = tt & 3;

  for (int kc = 0; kc < 32; ++kc) {
    int buf = kc & 1;
    {
      int node = b * S_ + kc * 32 + j;
      const unsigned short* p = qkvb + (size_t)node * 384 + (half ? 256 : 128) + h * 32 + seg * 8;
      short8 val = *(const short8*)p;
      if (half == 0) {
        *(short8*)&kL[buf][j][seg * 8] = val;
      } else {
#pragma unroll
        for (int i = 0; i < 8; ++i) vT[buf][seg * 8 + i][j] = (unsigned short)val[i];
      }
    }
    __syncthreads();
    short8 kB0 = *(const short8*)&kL[buf][li][quad * 8];
    short8 kB1 = *(const short8*)&kL[buf][16 + li][quad * 8];
    floatx4 z = {0.f, 0.f, 0.f, 0.f};
    floatx4 s0 = __builtin_amdgcn_mfma_f32_16x16x32_bf16(qA, kB0, z, 0, 0, 0);
    floatx4 s1 = __builtin_amdgcn_mfma_f32_16x16x32_bf16(qA, kB1, z, 0, 0, 0);
#pragma unroll
    for (int r = 0; r < 4; ++r) {
      float a0 = s0[r] * scale, a1 = s1[r] * scale;
      float cm = fmaxf(a0, a1);
#pragma unroll
      for (int msk = 1; msk <= 8; msk <<= 1) cm = fmaxf(cm, __shfl_xor(cm, msk));
      float mn = fmaxf(mreg[r], cm);
      float al = __expf(mreg[r] - mn);
      mreg[r] = mn;
      float p0 = __expf(a0 - mn), p1 = __expf(a1 - mn);
      float rs = p0 + p1;
#pragma unroll
      for (int msk = 1; msk <= 8; msk <<= 1) rs += __shfl_xor(rs, msk);
      lreg[r] = lreg[r] * al + rs;
      o0[r] *= al;
      o1[r] *= al;
      pL[w][quad * 4 + r][li] = f2bf_u(p0);
      pL[w][quad * 4 + r][16 + li] = f2bf_u(p1);
    }
    __syncthreads();
    short8 pA  = *(const short8*)&pL[w][li][quad * 8];
    short8 vB0 = *(const short8*)&vT[buf][li][quad * 8];
    short8 vB1 = *(const short8*)&vT[buf][16 + li][quad * 8];
    o0 = __builtin_amdgcn_mfma_f32_16x16x32_bf16(pA, vB0, o0, 0, 0, 0);
    o1 = __builtin_amdgcn_mfma_f32_16x16x32_bf16(pA, vB1, o1, 0, 0, 0);
  }
#pragma unroll
  for (int r = 0; r < 4; ++r) {
    float inv = 1.0f / lreg[r];
    size_t row = (size_t)(qbase + quad * 4 + r);
    attno[row * C_ + h * 32 + li] = o0[r] * inv;
    attno[row * C_ + h * 32 + 16 + li] = o1[r] * inv;
  }
}

// ------------- MFMA attn out proj + LN2 -------------
__global__ __launch_bounds__(256) void k_attnout_mfma(
    const float* __restrict__ attno, const float* __restrict__ x,
    const unsigned short* __restrict__ wt, const float* __restrict__ b,
    const float* __restrict__ g, const float* __restrict__ bln,
    float* __restrict__ ha) {
  __shared__ unsigned short inL[64][136];
  int tid = threadIdx.x;
  int row0 = blockIdx.x * 64;
#pragma unroll
  for (int i = 0; i < 8; ++i) {
    int p = i * 256 + tid;
    int r = p >> 5, c4 = p & 31;
    float4 xa = *(const float4*)(attno + (size_t)(row0 + r) * C_ + c4 * 4);
    ushort4 u;
    u.x = f2bf_u(xa.x); u.y = f2bf_u(xa.y); u.z = f2bf_u(xa.z); u.w = f2bf_u(xa.w);
    *(ushort4*)&inL[r][c4 * 4] = u;
  }
  __syncthreads();
  int lane = tid & 63, w = tid >> 6, li = lane & 15, quad = lane >> 4;
  int r0 = w * 16;
  short8 aK[4];
#pragma unroll
  for (int k4 = 0; k4 < 4; ++k4) aK[k4] = *(const short8*)&inL[r0 + li][k4 * 32 + quad * 8];
  floatx4 acc[8];
#pragma unroll
  for (int t8 = 0; t8 < 8; ++t8) acc[t8] = (floatx4){0.f, 0.f, 0.f, 0.f};
#pragma unroll
  for (int t8 = 0; t8 < 8; ++t8) {
    const unsigned short* bp = wt + (size_t)(t8 * 16 + li) * 128 + quad * 8;
#pragma unroll
    for (int k4 = 0; k4 < 4; ++k4) {
      short8 bf = *(const short8*)(bp + k4 * 32);
      acc[t8] = __builtin_amdgcn_mfma_f32_16x16x32_bf16(aK[k4], bf, acc[t8], 0, 0, 0);
    }
  }
  float gv[8], blv[8], bv[8];
#pragma unroll
  for (int t8 = 0; t8 < 8; ++t8) {
    int col = t8 * 16 + li;
    gv[t8] = g[col]; blv[t8] = bln[col]; bv[t8] = b[col];
  }
#pragma unroll
  for (int reg = 0; reg < 4; ++reg) {
    int row = row0 + r0 + quad * 4 + reg;
    float v[8], s = 0.f, s2 = 0.f;
#pragma unroll
    for (int t8 = 0; t8 < 8; ++t8) {
      float xv = x[(size_t)row * C_ + t8 * 16 + li];
      v[t8] = acc[t8][reg] + bv[t8] + xv;
      s += v[t8]; s2 += v[t8] * v[t8];
    }
#pragma unroll
    for (int m = 1; m <= 8; m <<= 1) { s += __shfl_xor(s, m); s2 += __shfl_xor(s2, m); }
    float mu = s * (1.0f / C_);
    float var = s2 * (1.0f / C_) - mu * mu;
    float inv = rsqrtf(var + LNE);
#pragma unroll
    for (int t8 = 0; t8 < 8; ++t8)
      ha[(size_t)row * C_ + t8 * 16 + li] = (v[t8] - mu) * inv * gv[t8] + blv[t8];
  }
}

// ------------- MFMA FFN: out=hl+ha; out+=MLP2(out,gelu); x += LN3(out) -------------
__global__ __launch_bounds__(256) void k_ffn_mfma(
    const float* __restrict__ hl, const float* __restrict__ ha,
    float* __restrict__ x,
    const unsigned short* __restrict__ w1t, const float* __restrict__ b1,
    const unsigned short* __restrict__ w2t, const float* __restrict__ b2,
    const float* __restrict__ g, const float* __restrict__ bln) {
  __shared__ unsigned short inL[64][136];
  __shared__ unsigned short hidL[64][264];
  int tid = threadIdx.x;
  int row0 = blockIdx.x * 64;
#pragma unroll
  for (int i = 0; i < 8; ++i) {
    int p = i * 256 + tid;
    int r = p >> 5, c4 = p & 31;
    float4 a = *(const float4*)(hl + (size_t)(row0 + r) * C_ + c4 * 4);
    float4 bq = *(const float4*)(ha + (size_t)(row0 + r) * C_ + c4 * 4);
    ushort4 u;
    u.x = f2bf_u(a.x + bq.x); u.y = f2bf_u(a.y + bq.y);
    u.z = f2bf_u(a.z + bq.z); u.w = f2bf_u(a.w + bq.w);
    *(ushort4*)&inL[r][c4 * 4] = u;
  }
  __syncthreads();
  int lane = tid & 63, w = tid >> 6, li = lane & 15, quad = lane >> 4;
  int r0 = w * 16;
  short8 aK[4];
#pragma unroll
  for (int k4 = 0; k4 < 4; ++k4) aK[k4] = *(const short8*)&inL[r0 + li][k4 * 32 + quad * 8];
  floatx4 acc1[16];
#pragma unroll
  for (int t8 = 0; t8 < 16; ++t8) acc1[t8] = (floatx4){0.f, 0.f, 0.f, 0.f};
#pragma unroll
  for (int t8 = 0; t8 < 16; ++t8) {
    const unsigned short* bp = w1t + (size_t)(t8 * 16 + li) * 128 + quad * 8;
#pragma unroll
    for (int k4 = 0; k4 < 4; ++k4) {
      short8 bf = *(const short8*)(bp + k4 * 32);
      acc1[t8] = __builtin_amdgcn_mfma_f32_16x16x32_bf16(aK[k4], bf, acc1[t8], 0, 0, 0);
    }
  }
  // gelu -> hidL (wave-private rows)
#pragma unroll
  for (int t8 = 0; t8 < 16; ++t8) {
    float bv = b1[t8 * 16 + li];
#pragma unroll
    for (int reg = 0; reg < 4; ++reg)
      hidL[r0 + quad * 4 + reg][t8 * 16 + li] = f2bf_u(gelu_tanh(acc1[t8][reg] + bv));
  }
  short8 aK2[8];
#pragma unroll
  for (int k4 = 0; k4 < 8; ++k4) aK2[k4] = *(const short8*)&hidL[r0 + li][k4 * 32 + quad * 8];
  floatx4 acc2[8];
#pragma unroll
  for (int t8 = 0; t8 < 8; ++t8) acc2[t8] = (floatx4){0.f, 0.f, 0.f, 0.f};
#pragma unroll
  for (int t8 = 0; t8 < 8; ++t8) {
    const unsigned short* bp = w2t + (size_t)(t8 * 16 + li) * 256 + quad * 8;
#pragma unroll
    for (int k4 = 0; k4 < 8; ++k4) {
      short8 bf = *(const short8*)(bp + k4 * 32);
      acc2[t8] = __builtin_amdgcn_mfma_f32_16x16x32_bf16(aK2[k4], bf, acc2[t8], 0, 0, 0);
    }
  }
  float gv[8], blv[8], b2v[8];
#pragma unroll
  for (int t8 = 0; t8 < 8; ++t8) {
    int col = t8 * 16 + li;
    gv[t8] = g[col]; blv[t8] = bln[col]; b2v[t8] = b2[col];
  }
#pragma unroll
  for (int reg = 0; reg < 4; ++reg) {
    int row = row0 + r0 + quad * 4 + reg;
    float v[8], s = 0.f, s2 = 0.f;
#pragma unroll
    for (int t8 = 0; t8 < 8; ++t8) {
      size_t idx = (size_t)row * C_ + t8 * 16 + li;
      float outv = hl[idx] + ha[idx];
      v[t8] = acc2[t8][reg] + b2v[t8] + outv;
      s += v[t8]; s2 += v[t8] * v[t8];
    }
#pragma unroll
    for (int m = 1; m <= 8; m <<= 1) { s += __shfl_xor(s, m); s2 += __shfl_xor(s2, m); }
    float mu = s * (1.0f / C_);
    float var = s2 * (1.0f / C_) - mu * mu;
    float inv = rsqrtf(var + LNE);
#pragma unroll
    for (int t8 = 0; t8 < 8; ++t8) {
      size_t idx = (size_t)row * C_ + t8 * 16 + li;
      x[idx] = x[idx] + (v[t8] - mu) * inv * gv[t8] + blv[t8];
    }
  }
}

// ------------- post MLP (scalar fp32, kept for accuracy: feeds readout directly) -------------
__global__ void k_post(float* __restrict__ x,
                       const float* __restrict__ w1, const float* __restrict__ b1,
                       const float* __restrict__ w2, const float* __restrict__ b2) {
  __shared__ float inL[4][C_];
  __shared__ float hidL[4][C_];
  int t = threadIdx.x;
  int row0 = blockIdx.x * 4;
  float xv[4];
#pragma unroll
  for (int r = 0; r < 4; ++r) {
    size_t idx = (size_t)(row0 + r) * C_ + t;
    xv[r] = x[idx];
    inL[r][t] = xv[r];
  }
  __syncthreads();
  float acc[4];
  float bb = b1[t];
#pragma unroll
  for (int r = 0; r < 4; ++r) acc[r] = bb;
  for (int k = 0; k < C_; ++k) {
    float wv = w1[k * C_ + t];
#pragma unroll
    for (int r = 0; r < 4; ++r) acc[r] += inL[r][k] * wv;
  }
#pragma unroll
  for (int r = 0; r < 4; ++r) hidL[r][t] = fmaxf(acc[r], 0.0f);
  __syncthreads();
  float bb2 = b2[t];
#pragma unroll
  for (int r = 0; r < 4; ++r) acc[r] = bb2;
  for (int k = 0; k < C_; ++k) {
    float wv = w2[k * C_ + t];
#pragma unroll
    for (int r = 0; r < 4; ++r) acc[r] += hidL[r][k] * wv;
  }
#pragma unroll
  for (int r = 0; r < 4; ++r) {
    size_t idx = (size_t)(row0 + r) * C_ + t;
    x[idx] = xv[r] + acc[r];
  }
}

// ------------- mean pool per graph -------------
__global__ void k_pool(const float* __restrict__ x, float* __restrict__ gmean) {
  int t = threadIdx.x;
  int b = blockIdx.x;
  float s = 0.0f;
  for (int sidx = 0; sidx < S_; ++sidx) s += x[((size_t)b * S_ + sidx) * C_ + t];
  gmean[b * C_ + t] = s * (1.0f / S_);
}

// ------------- readout -------------
__global__ void k_readout(const float* __restrict__ gmean,
                          const float* __restrict__ w1, const float* __restrict__ b1,
                          const float* __restrict__ w2, const float* __restrict__ b2,
                          float* __restrict__ out) {
  __shared__ float gL[C_];
  __shared__ float red[C_];
  int t = threadIdx.x;
  int b = blockIdx.x;
  gL[t] = gmean[b * C_ + t];
  __syncthreads();
  float acc = b1[t];
  for (int k = 0; k < C_; ++k) acc += gL[k] * w1[k * C_ + t];
  float hid = fmaxf(acc, 0.0f);
  float part = hid * w2[t];
  float tot = block_sum128(part, red, t);
  if (t == 0) out[b] = tot + b2[0];
}

}  // namespace

extern "C" void kernel_launch(void* const* d_in, const int* in_sizes, int n_in,
                              void* d_out, int out_size, void* d_ws, size_t ws_size,
                              hipStream_t stream) {
  const float* in_x      = (const float*)d_in[0];
  const int*   edge_idx  = (const int*)d_in[1];
  const float* edge_attr = (const float*)d_in[3];
  const float* lap_pe    = (const float*)d_in[4];
  const float* node_w1 = (const float*)d_in[5];
  const float* node_b1 = (const float*)d_in[6];
  const float* node_w2 = (const float*)d_in[7];
  const float* node_b2 = (const float*)d_in[8];
  const float* edge_w1 = (const float*)d_in[9];
  const float* edge_b1 = (const float*)d_in[10];
  const float* edge_w2 = (const float*)d_in[11];
  const float* edge_b2 = (const float*)d_in[12];
  const float* eps     = (const float*)d_in[13];
  const float* gin_w1  = (const float*)d_in[14];
  const float* gin_b1  = (const float*)d_in[15];
  const float* gin_w2  = (const float*)d_in[16];
  const float* gin_b2  = (const float*)d_in[17];
  const float* elin_w  = (const float*)d_in[18];
  const float* elin_b  = (const float*)d_in[19];
  const float* aqkv_w  = (const float*)d_in[20];
  const float* aqkv_b  = (const float*)d_in[21];
  const float* aout_w  = (const float*)d_in[22];
  const float* aout_b  = (const float*)d_in[23];
  const float* mlp_w1  = (const float*)d_in[24];
  const float* mlp_b1  = (const float*)d_in[25];
  const float* mlp_w2  = (const float*)d_in[26];
  const float* mlp_b2  = (const float*)d_in[27];
  const float* ln1_g   = (const float*)d_in[28];
  const float* ln1_b   = (const float*)d_in[29];
  const float* ln2_g   = (const float*)d_in[30];
  const float* ln2_b   = (const float*)d_in[31];
  const float* ln3_g   = (const float*)d_in[32];
  const float* ln3_b   = (const float*)d_in[33];
  const float* post_w1 = (const float*)d_in[34];
  const float* post_b1 = (const float*)d_in[35];
  const float* post_w2 = (const float*)d_in[36];
  const float* post_b2 = (const float*)d_in[37];
  const float* ro_w1   = (const float*)d_in[38];
  const float* ro_b1   = (const float*)d_in[39];
  const float* ro_w2   = (const float*)d_in[40];
  const float* ro_b2   = (const float*)d_in[41];

  const int* src = edge_idx;
  const int* dst = edge_idx + E_;

  // Workspace (floats): x NC | region2 1.5NC (agg fp32 / qkvb bf16, disjoint lifetimes)
  //                    | hl NC | attno NC | fb2 | fw2tb bf16 | wt bf16   (~77 MB)
  float* ws = (float*)d_ws;
  float* x     = ws;                                  // N*C
  float* region2 = x + (size_t)N_ * C_;               // N*192 floats
  float* agg   = region2;                             // N*C fp32 (within region2)
  unsigned short* qkvb = (unsigned short*)region2;    // N*384 bf16
  float* hl    = region2 + (size_t)N_ * 192;          // N*C
  float* attno = hl + (size_t)N_ * C_;                // N*C
  float* ha    = attno;                               // in-place
  float* fb2   = attno + (size_t)N_ * C_;             // L*C floats
  unsigned short* fw2tb = (unsigned short*)(fb2 + 4 * C_);  // L*C*C bf16
  unsigned short* wt = fw2tb + (size_t)4 * C_ * C_;   // 655360 bf16 node weights
  float* gmean = hl;                                  // alias

  float* out = (float*)d_out;

  dim3 blk(128);
  const size_t LWS = 163840;  // per-layer wt stride (bf16 elems)

  k_fuse_w<<<4 * (C_ + 1), blk, 0, stream>>>(edge_w2, edge_b2, elin_w, elin_b, fw2tb, fb2);
  k_prep<<<4 * 1152, blk, 0, stream>>>(gin_w1, gin_w2, aqkv_w, aout_w, mlp_w1, mlp_w2, wt);
  k_node_enc<<<N_ / 4, blk, 0, stream>>>(in_x, lap_pe, node_w1, node_b1, node_w2, node_b2, x);

  for (int i = 0; i < 4; ++i) {
    const unsigned short* wl = wt + (size_t)i * LWS;
    k_zero<<<(N_ * C_ / 4 + 255) / 256, 256, 0, stream>>>((float4*)agg, N_ * C_ / 4);
    k_edge_mfma<<<E_ / 64, 256, 0, stream>>>(edge_attr, x, src, dst,
                                             edge_w1, edge_b1,
                                             fw2tb + (size_t)i * C_ * C_, fb2 + i * C_, agg);
    k_gin_mfma<<<N_ / 64, 256, 0, stream>>>(x, agg,
                                            wl + 0, gin_b1 + i * C_,
                                            wl + 16384, gin_b2 + i * C_,
                                            ln1_g + i * C_, ln1_b + i * C_, eps, i, hl);
    k_qkv_mfma<<<N_ / 64, 256, 0, stream>>>(x, wl + 32768, aqkv_b + i * 384, qkvb);
    k_attn_mfma<<<B_ * 4 * 16, 256, 0, stream>>>(qkvb, attno);
    k_attnout_mfma<<<N_ / 64, 256, 0, stream>>>(attno, x,
                                                wl + 81920, aout_b + i * C_,
                                                ln2_g + i * C_, ln2_b + i * C_, ha);
    k_ffn_mfma<<<N_ / 64, 256, 0, stream>>>(hl, ha, x,
                                            wl + 98304, mlp_b1 + i * 256,
                                            wl + 131072, mlp_b2 + i * C_,
                                            ln3_g + i * C_, ln3_b + i * C_);
  }

  k_post<<<N_ / 4, blk, 0, stream>>>(x, post_w1, post_b1, post_w2, post_b2);
  k_pool<<<B_, blk, 0, stream>>>(x, gmean);
  k_readout<<<B_, blk, 0, stream>>>(gmean, ro_w1, ro_b1, ro_w2, ro_b2, out);
}